// Round 5
// baseline (4797.548 us; speedup 1.0000x reference)
//
#include <hip/hip_runtime.h>
#include <hip/hip_bf16.h>

// Problem constants
#define NB   32
#define LL   320
#define CC   768
#define NH   12
#define DHD  64
#define LT   64
#define LSN  256
#define NKEEP 180
#define NREM  76
#define LP   244
#define ADH  64
#define C4   3072

// ---------------- reductions ----------------
__device__ __forceinline__ float blk_sum(float v, float* sh){
  #pragma unroll
  for (int o = 32; o > 0; o >>= 1) v += __shfl_down(v, o, 64);
  int w = threadIdx.x >> 6;
  if ((threadIdx.x & 63) == 0) sh[w] = v;
  __syncthreads();
  float r = sh[0] + sh[1] + sh[2] + sh[3];
  __syncthreads();
  return r;
}

// ---------------- LayerNorm (row = 768) ----------------
__global__ __launch_bounds__(256) void ln_k(const float* __restrict__ x,
                                            const float* __restrict__ g,
                                            const float* __restrict__ be,
                                            float* __restrict__ y){
  __shared__ float sh[4];
  size_t row = blockIdx.x;
  const float* xr = x + row * CC;
  int t = threadIdx.x;
  float v0 = xr[t], v1 = xr[t + 256], v2 = xr[t + 512];
  float m = blk_sum(v0 + v1 + v2, sh) * (1.0f / 768.0f);
  float d0 = v0 - m, d1 = v1 - m, d2 = v2 - m;
  float var = blk_sum(d0*d0 + d1*d1 + d2*d2, sh) * (1.0f / 768.0f);
  float rs = rsqrtf(var + 1e-5f);
  float* yr = y + row * CC;
  yr[t]       = d0 * rs * g[t]       + be[t];
  yr[t + 256] = d1 * rs * g[t + 256] + be[t + 256];
  yr[t + 512] = d2 * rs * g[t + 512] + be[t + 512];
}

// ---------------- generic f32 GEMM: C = [ACC +=] act(A[M,K] @ W[K,N] + bias) ----------------
template<bool GELU, bool ACC>
__global__ __launch_bounds__(256) void gemm_k(const float* __restrict__ A,
                                              const float* __restrict__ W,
                                              const float* __restrict__ bias,
                                              float* __restrict__ Cm,
                                              int M, int N, int K){
  __shared__ float As[16][65];
  __shared__ float Bs[16][64];
  const int t = threadIdx.x;
  const int tx = t & 15, ty = t >> 4;
  const int m0 = blockIdx.y * 64, n0 = blockIdx.x * 64;
  const int akk = t & 15, amm = t >> 4;
  const int bnn = t & 63, bkk = t >> 6;
  float acc[4][4] = {};
  for (int k0 = 0; k0 < K; k0 += 16){
    #pragma unroll
    for (int q = 0; q < 4; q++)
      As[akk][amm + 16*q] = A[(size_t)(m0 + amm + 16*q) * K + k0 + akk];
    #pragma unroll
    for (int q = 0; q < 4; q++)
      Bs[bkk + 4*q][bnn] = W[(size_t)(k0 + bkk + 4*q) * N + n0 + bnn];
    __syncthreads();
    #pragma unroll
    for (int kk = 0; kk < 16; kk++){
      float a[4], b[4];
      #pragma unroll
      for (int i = 0; i < 4; i++) a[i] = As[kk][ty*4 + i];
      #pragma unroll
      for (int j = 0; j < 4; j++) b[j] = Bs[kk][tx*4 + j];
      #pragma unroll
      for (int i = 0; i < 4; i++)
        #pragma unroll
        for (int j = 0; j < 4; j++)
          acc[i][j] = fmaf(a[i], b[j], acc[i][j]);
    }
    __syncthreads();
  }
  #pragma unroll
  for (int i = 0; i < 4; i++){
    int m = m0 + ty*4 + i;
    #pragma unroll
    for (int j = 0; j < 4; j++){
      int n = n0 + tx*4 + j;
      float v = acc[i][j];
      if (bias) v += bias[n];
      if (GELU) v = 0.5f * v * (1.0f + erff(v * 0.70710678118654752f));
      size_t idx = (size_t)m * N + n;
      if (ACC) Cm[idx] += v; else Cm[idx] = v;
    }
  }
}

// ---------------- scores = (q @ k^T) * 0.125, written into d_out attn region ----------------
__global__ __launch_bounds__(256) void scores_k(const float* __restrict__ qkv,
                                                float* __restrict__ sc){
  __shared__ float Qs[16][65];
  __shared__ float Ks[16][65];
  const int t = threadIdx.x, tx = t & 15, ty = t >> 4;
  const int bh = blockIdx.z; const int b = bh / NH, h = bh % NH;
  const int i0 = blockIdx.y * 64, j0 = blockIdx.x * 64;
  const size_t qbase = (size_t)b * LL * 2304 + (size_t)h * 64;
  const size_t kbase = qbase + 768;
  const int lkk = t & 15, lmm = t >> 4;
  float acc[4][4] = {};
  for (int d0 = 0; d0 < DHD; d0 += 16){
    #pragma unroll
    for (int q = 0; q < 4; q++)
      Qs[lkk][lmm + 16*q] = qkv[qbase + (size_t)(i0 + lmm + 16*q) * 2304 + d0 + lkk];
    #pragma unroll
    for (int q = 0; q < 4; q++)
      Ks[lkk][lmm + 16*q] = qkv[kbase + (size_t)(j0 + lmm + 16*q) * 2304 + d0 + lkk];
    __syncthreads();
    #pragma unroll
    for (int kk = 0; kk < 16; kk++){
      float a[4], b2[4];
      #pragma unroll
      for (int i = 0; i < 4; i++) a[i] = Qs[kk][ty*4 + i];
      #pragma unroll
      for (int j = 0; j < 4; j++) b2[j] = Ks[kk][tx*4 + j];
      #pragma unroll
      for (int i = 0; i < 4; i++)
        #pragma unroll
        for (int j = 0; j < 4; j++)
          acc[i][j] = fmaf(a[i], b2[j], acc[i][j]);
    }
    __syncthreads();
  }
  #pragma unroll
  for (int i = 0; i < 4; i++)
    #pragma unroll
    for (int j = 0; j < 4; j++)
      sc[((size_t)bh * LL + i0 + ty*4 + i) * LL + j0 + tx*4 + j] = acc[i][j] * 0.125f;
}

// ---------------- row softmax over 320, in place (f32 probs = final attn output) ----------------
__global__ __launch_bounds__(256) void softmax_k(float* __restrict__ sc){
  const int lane = threadIdx.x & 63;
  const size_t row = (size_t)blockIdx.x * 4 + (threadIdx.x >> 6);
  float* sr = sc + row * LL;
  float v[5]; float mx = -3.4e38f;
  #pragma unroll
  for (int i = 0; i < 5; i++){ v[i] = sr[lane + 64*i]; mx = fmaxf(mx, v[i]); }
  #pragma unroll
  for (int o = 32; o > 0; o >>= 1) mx = fmaxf(mx, __shfl_xor(mx, o, 64));
  float s = 0.f;
  #pragma unroll
  for (int i = 0; i < 5; i++){ v[i] = expf(v[i] - mx); s += v[i]; }
  #pragma unroll
  for (int o = 32; o > 0; o >>= 1) s += __shfl_xor(s, o, 64);
  float inv = 1.0f / s;
  #pragma unroll
  for (int i = 0; i < 5; i++) sr[lane + 64*i] = v[i] * inv;
}

// ---------------- attn_t[b][j] = mean over h,i<64 of probs (f64 accumulate) ----------------
__global__ __launch_bounds__(256) void attnt_k(const float* __restrict__ probs,
                                               float* __restrict__ at){
  int b = blockIdx.x, j = threadIdx.x;
  double s = 0.0;
  for (int h = 0; h < NH; h++)
    for (int i = 0; i < LT; i++)
      s += (double)probs[(((size_t)b * NH + h) * LL + i) * LL + 64 + j];
  at[b * LSN + j] = (float)(s * (1.0 / 768.0));
}

// ---------------- PV: out[b,i,h*64+d] = sum_j p[b,h,i,j] * v[b,j,h,d] ----------------
__global__ __launch_bounds__(256) void pv_k(const float* __restrict__ probs,
                                            const float* __restrict__ qkv,
                                            float* __restrict__ pv){
  __shared__ float As[16][65];
  __shared__ float Bs[16][64];
  const int t = threadIdx.x, tx = t & 15, ty = t >> 4;
  const int bh = blockIdx.y; const int b = bh / NH, h = bh % NH;
  const int i0 = blockIdx.x * 64;
  const size_t vbase = (size_t)b * LL * 2304 + 1536 + (size_t)h * 64;
  const int akk = t & 15, amm = t >> 4;
  const int bnn = t & 63, bkk = t >> 6;
  const float* Ap = probs + (size_t)bh * LL * LL;
  float acc[4][4] = {};
  for (int k0 = 0; k0 < LL; k0 += 16){
    #pragma unroll
    for (int q = 0; q < 4; q++)
      As[akk][amm + 16*q] = Ap[(size_t)(i0 + amm + 16*q) * LL + k0 + akk];
    #pragma unroll
    for (int q = 0; q < 4; q++)
      Bs[bkk + 4*q][bnn] = qkv[vbase + (size_t)(k0 + bkk + 4*q) * 2304 + bnn];
    __syncthreads();
    #pragma unroll
    for (int kk = 0; kk < 16; kk++){
      float a[4], b2[4];
      #pragma unroll
      for (int i = 0; i < 4; i++) a[i] = As[kk][ty*4 + i];
      #pragma unroll
      for (int j = 0; j < 4; j++) b2[j] = Bs[kk][tx*4 + j];
      #pragma unroll
      for (int i = 0; i < 4; i++)
        #pragma unroll
        for (int j = 0; j < 4; j++)
          acc[i][j] = fmaf(a[i], b2[j], acc[i][j]);
    }
    __syncthreads();
  }
  #pragma unroll
  for (int i = 0; i < 4; i++)
    #pragma unroll
    for (int j = 0; j < 4; j++)
      pv[((size_t)b * LL + i0 + ty*4 + i) * CC + h*64 + tx*4 + j] = acc[i][j];
}

// ---------------- CE: identity init -> rank -> emit (f32 index outputs) ----------------
__global__ __launch_bounds__(256) void init_ord_k(int* __restrict__ ordbuf, int n){
  int i = blockIdx.x * 256 + threadIdx.x;
  if (i < n) ordbuf[i] = i & 255;
}

__global__ __launch_bounds__(256) void ce_rank_k(const float* __restrict__ at,
                                                 int* __restrict__ ordbuf){
  __shared__ float a[256];
  int b = blockIdx.x, t = threadIdx.x;
  a[t] = at[b * LSN + t];
  __syncthreads();
  float mine = a[t];
  int rank = 0;
  for (int k = 0; k < 256; k++){
    float ak = a[k];
    rank += (ak > mine) || (ak == mine && k < t);
  }
  if (rank >= 0 && rank < 256) ordbuf[b * LSN + rank] = t;
}

__global__ __launch_bounds__(256) void ce_emit_k(const int* __restrict__ ordbuf,
                                                 const int* __restrict__ gidx,
                                                 const int* __restrict__ gt,
                                                 float* __restrict__ out_keep,
                                                 float* __restrict__ out_rem,
                                                 float* __restrict__ out_git){
  int b = blockIdx.x, t = threadIdx.x;
  int o = ordbuf[b * LSN + t];
  o = min(max(o, 0), 255);
  int idx = gidx[b * LSN + o];
  if (t < NKEEP) out_keep[b * NKEEP + t] = (float)idx;
  else           out_rem[b * NREM + (t - NKEEP)] = (float)idx;
  if (t < LT)    out_git[b * LT + t] = (float)gt[b * LT + t];
}

// ---------------- gather pruned tokens ----------------
__global__ __launch_bounds__(256) void gather_k(const float* __restrict__ xnew,
                                                const int* __restrict__ ordbuf,
                                                float* __restrict__ x2){
  int row = blockIdx.x;           // b*244 + r
  int b = row / LP, r = row % LP;
  int o = (r < LT) ? 0 : ordbuf[b * LSN + (r - LT)];
  o = min(max(o, 0), 255);
  int src = (r < LT) ? r : (LT + o);
  const float* s = xnew + ((size_t)b * LL + src) * CC;
  float* d = x2 + (size_t)row * CC;
  for (int i = threadIdx.x; i < CC; i += 256) d[i] = s[i];
}

// ---------------- elementwise ----------------
__global__ void add_k(float* __restrict__ d, const float* __restrict__ s, size_t n){
  size_t i = (size_t)blockIdx.x * 256 + threadIdx.x;
  size_t st = (size_t)gridDim.x * 256;
  for (; i < n; i += st) d[i] += s[i];
}
__global__ void sentinel_k(float* __restrict__ d, float val, int n){
  int i = blockIdx.x * 256 + threadIdx.x;
  if (i < n) d[i] = val;
}

// ======================================================================
extern "C" void kernel_launch(void* const* d_in, const int* in_sizes, int n_in,
                              void* d_out, int out_size, void* d_ws, size_t ws_size,
                              hipStream_t stream) {
  float* out = (float*)d_out;          // f32 output buffer (ref outputs are f32/int32)
  float* ws  = (float*)d_ws;

  static const int EXP[26] = {
    7864320, 7864320, 2048, 2048, 8192, 8192, 1,
    768, 768, 1769472, 589824, 768, 768, 768,
    2359296, 3072, 2359296, 768,
    49152, 64, 49152, 768, 49152, 64, 49152, 768 };

  const void* P[26];
  bool ok = false;
  if (n_in == 26){
    bool m = true; int bad = -1;
    for (int i = 0; i < 26; i++) if (in_sizes[i] != EXP[i]){ m = false; bad = i; break; }
    if (m){ for (int i = 0; i < 26; i++) P[i] = d_in[i]; ok = true; }
    else { sentinel_k<<<16, 256, 0, stream>>>(out, 20000.0f + 16.0f*bad, 4096); return; }
  } else if (n_in == 25){
    bool m = true; int bad = -1;
    for (int i = 0; i < 25; i++){
      int j = (i < 6) ? i : i + 1;
      if (in_sizes[i] != EXP[j]){ m = false; bad = i; break; }
    }
    if (m){
      for (int j = 0; j < 26; j++) P[j] = (j == 6) ? nullptr : d_in[(j < 6) ? j : j - 1];
      ok = true;
    } else { sentinel_k<<<16, 256, 0, stream>>>(out, 20000.0f + 16.0f*bad, 4096); return; }
  }
  if (!ok){ sentinel_k<<<16, 256, 0, stream>>>(out, 10000.0f + 8.0f*n_in, 4096); return; }
  if (out_size != 90656768){
    sentinel_k<<<16, 256, 0, stream>>>(out, 60000.0f + (float)(out_size / 1000000), 4096); return;
  }

  const float* x      = (const float*)P[0];
  const float* xi     = (const float*)P[1];
  const int*   gi_t   = (const int*)P[2];
  const int*   gi_ti  = (const int*)P[3];
  const int*   gi_s   = (const int*)P[4];
  const int*   gi_si  = (const int*)P[5];
  const float* n1_g   = (const float*)P[7];
  const float* n1_b   = (const float*)P[8];
  const float* qkv_w  = (const float*)P[9];
  const float* proj_w = (const float*)P[10];
  const float* proj_b = (const float*)P[11];
  const float* n2_g   = (const float*)P[12];
  const float* n2_b   = (const float*)P[13];
  const float* fc1_w  = (const float*)P[14];
  const float* fc1_b  = (const float*)P[15];
  const float* fc2_w  = (const float*)P[16];
  const float* fc2_b  = (const float*)P[17];
  const float* ad1_dw = (const float*)P[18];
  const float* ad1_db = (const float*)P[19];
  const float* ad1_uw = (const float*)P[20];
  const float* ad1_ub = (const float*)P[21];
  const float* ad2_dw = (const float*)P[22];
  const float* ad2_db = (const float*)P[23];
  const float* ad2_uw = (const float*)P[24];
  const float* ad2_ub = (const float*)P[25];

  // output offsets (f32 elements), reference return order
  const size_t o_x     = 0;
  const size_t o_git   = 5996544;
  const size_t o_gis   = 5998592;
  const size_t o_rem   = 6004352;
  const size_t o_attn  = 6006784;
  const size_t o_xi    = 45328384;
  const size_t o_giti  = 51324928;
  const size_t o_gisi  = 51326976;
  const size_t o_remi  = 51332736;
  const size_t o_iattn = 51335168;

  // workspace layout (f32 elements) — 257 MB total (scores live in d_out now)
  const size_t BLC      = (size_t)NB * LL * CC;            // 7,864,320
  const size_t BPC      = (size_t)NB * LP * CC;            // 5,996,544
  const size_t off_ln   = 0;                               // 2*BLC; phase B: x2 (2*BPC)
  const size_t off_qkv  = off_ln  + 2 * BLC;               // 23,592,960; phase B: hid
  const size_t off_pv   = off_qkv + (size_t)NB*LL*3*CC;    // BLC (hid spills here in B, dead)
  const size_t off_xnew = off_pv  + BLC;                   // 2*BLC; phase B: ln2 (2*BPC)
  const size_t off_mixh = off_xnew+ 2 * BLC;               // 1,310,720
  const size_t off_att  = off_mixh+ (size_t)2*NB*LL*ADH;   // 16,384
  const size_t off_ord  = off_att + 2 * (size_t)NB*LSN;    // 16,384 ints
  const size_t total_f  = off_ord + 2 * (size_t)NB*LSN;    // 64,258,048 = 257 MB
  if (ws_size < total_f * sizeof(float)){
    sentinel_k<<<16, 256, 0, stream>>>(out, 40000.0f + (float)(ws_size >> 20), 4096);
    return;
  }

  int* ordbuf = (int*)(ws + off_ord);

  // ---- Phase A: LN1 + adapter-down for both streams ----
  ln_k<<<NB*LL, 256, 0, stream>>>(x,  n1_g, n1_b, ws + off_ln);
  ln_k<<<NB*LL, 256, 0, stream>>>(xi, n1_g, n1_b, ws + off_ln + BLC);
  gemm_k<true,false><<<dim3(1, 320), 256, 0, stream>>>(
      ws + off_ln, ad1_dw, ad1_db, ws + off_mixh, 2*NB*LL, ADH, CC);

  // ---- attention per stream (scores/probs live directly in d_out attn region) ----
  for (int s = 0; s < 2; s++){
    const float* xin  = s ? xi : x;
    const float* ln_s = ws + off_ln + (size_t)s * BLC;
    float* xnew_s     = ws + off_xnew + (size_t)s * BLC;
    float* probs      = out + (s ? o_iattn : o_attn);
    gemm_k<false,false><<<dim3(36, 160), 256, 0, stream>>>(
        ln_s, qkv_w, nullptr, ws + off_qkv, NB*LL, 3*CC, CC);
    scores_k<<<dim3(5, 5, NB*NH), 256, 0, stream>>>(ws + off_qkv, probs);
    softmax_k<<<NB*NH*LL/4, 256, 0, stream>>>(probs);
    attnt_k<<<NB, 256, 0, stream>>>(probs, ws + off_att + (size_t)s * NB * LSN);
    pv_k<<<dim3(5, NB*NH), 256, 0, stream>>>(probs, ws + off_qkv, ws + off_pv);
    gemm_k<false,false><<<dim3(12, 160), 256, 0, stream>>>(
        ws + off_pv, proj_w, proj_b, xnew_s, NB*LL, CC, CC);
    add_k<<<4096, 256, 0, stream>>>(xnew_s, xin, BLC);
    gemm_k<false,true><<<dim3(12, 160), 256, 0, stream>>>(
        ws + off_mixh + (size_t)(1 - s) * NB * LL * ADH, ad1_uw, ad1_ub,
        xnew_s, NB*LL, CC, ADH);
  }

  // ---- CE: rank by attn_t, emit f32 index outputs, gather tokens ----
  init_ord_k<<<(2*NB*LSN + 255)/256, 256, 0, stream>>>(ordbuf, 2*NB*LSN);
  for (int s = 0; s < 2; s++){
    ce_rank_k<<<NB, 256, 0, stream>>>(
        ws + off_att + (size_t)s * NB * LSN, ordbuf + (size_t)s * NB * LSN);
    ce_emit_k<<<NB, 256, 0, stream>>>(
        ordbuf + (size_t)s * NB * LSN,
        s ? gi_si : gi_s, s ? gi_ti : gi_t,
        out + (s ? o_gisi : o_gis), out + (s ? o_remi : o_rem),
        out + (s ? o_giti : o_git));
    gather_k<<<NB*LP, 256, 0, stream>>>(
        ws + off_xnew + (size_t)s * BLC,
        ordbuf + (size_t)s * NB * LSN,
        ws + off_ln + (size_t)s * BPC);          // x2 -> dead LN1 region
  }

  // ---- Phase B: LN2, adapters, MLP on 244 tokens; xout lives in d_out ----
  float* x2    = ws + off_ln;       // [2][B*244][C]
  float* ln2   = ws + off_xnew;     // [2][B*244][C]  (xnew dead after gather)
  float* mixh2 = ws + off_mixh;     // [2][B*244][64]
  float* hid   = ws + off_qkv;      // [B*244][3072]  (spills into dead pv region)

  ln_k<<<NB*LP, 256, 0, stream>>>(x2,        n2_g, n2_b, ln2);
  ln_k<<<NB*LP, 256, 0, stream>>>(x2 + BPC,  n2_g, n2_b, ln2 + BPC);
  gemm_k<true,false><<<dim3(1, 244), 256, 0, stream>>>(
      ln2, ad2_dw, ad2_db, mixh2, 2*NB*LP, ADH, CC);

  for (int s = 0; s < 2; s++){
    float* xout = out + (s ? o_xi : o_x);      // write final x/xi directly in d_out
    gemm_k<true,false><<<dim3(48, 122), 256, 0, stream>>>(
        ln2 + (size_t)s * BPC, fc1_w, fc1_b, hid, NB*LP, C4, CC);
    gemm_k<false,false><<<dim3(12, 122), 256, 0, stream>>>(
        mixh2 + (size_t)(1 - s) * NB * LP * ADH, ad2_uw, ad2_ub, xout, NB*LP, CC, ADH);
    add_k<<<4096, 256, 0, stream>>>(xout, x2 + (size_t)s * BPC, BPC);
    gemm_k<false,true><<<dim3(12, 122), 256, 0, stream>>>(
        hid, fc2_w, fc2_b, xout, NB*LP, CC, C4);
  }
}

// Round 6
// 2360.326 us; speedup vs baseline: 2.0326x; 2.0326x over previous
//
#include <hip/hip_runtime.h>
#include <hip/hip_bf16.h>

// Problem constants
#define NB   32
#define LL   320
#define CC   768
#define NH   12
#define DHD  64
#define LT   64
#define LSN  256
#define NKEEP 180
#define NREM  76
#define LP   244
#define ADH  64
#define C4   3072
#define QS   1536    // Q,K buffer row stride

typedef __attribute__((ext_vector_type(8))) short s16x8;
typedef __attribute__((ext_vector_type(4))) float f32x4;

__device__ __forceinline__ ushort f2b(float f){
  union { __hip_bfloat16 h; ushort u; } cv;
  cv.h = __float2bfloat16(f);
  return cv.u;
}

// ---------------- reductions ----------------
__device__ __forceinline__ float blk_sum(float v, float* sh){
  #pragma unroll
  for (int o = 32; o > 0; o >>= 1) v += __shfl_down(v, o, 64);
  int w = threadIdx.x >> 6;
  if ((threadIdx.x & 63) == 0) sh[w] = v;
  __syncthreads();
  float r = sh[0] + sh[1] + sh[2] + sh[3];
  __syncthreads();
  return r;
}

// ---------------- LayerNorm (row = 768), optional bf16 secondary output ----------------
__global__ __launch_bounds__(256) void ln_k(const float* __restrict__ x,
                                            const float* __restrict__ g,
                                            const float* __restrict__ be,
                                            float* __restrict__ y,
                                            ushort* __restrict__ yb){
  __shared__ float sh[4];
  size_t row = blockIdx.x;
  const float* xr = x + row * CC;
  int t = threadIdx.x;
  float v0 = xr[t], v1 = xr[t + 256], v2 = xr[t + 512];
  float m = blk_sum(v0 + v1 + v2, sh) * (1.0f / 768.0f);
  float d0 = v0 - m, d1 = v1 - m, d2 = v2 - m;
  float var = blk_sum(d0*d0 + d1*d1 + d2*d2, sh) * (1.0f / 768.0f);
  float rs = rsqrtf(var + 1e-5f);
  float o0 = d0 * rs * g[t]       + be[t];
  float o1 = d1 * rs * g[t + 256] + be[t + 256];
  float o2 = d2 * rs * g[t + 512] + be[t + 512];
  float* yr = y + row * CC;
  yr[t] = o0; yr[t + 256] = o1; yr[t + 512] = o2;
  if (yb){
    ushort* yr2 = yb + row * CC;
    yr2[t] = f2b(o0); yr2[t + 256] = f2b(o1); yr2[t + 512] = f2b(o2);
  }
}

// ---------------- generic f32 GEMM (ldw/ldc parameterized) ----------------
template<bool GELU, bool ACC>
__global__ __launch_bounds__(256) void gemm_k(const float* __restrict__ A,
                                              const float* __restrict__ W,
                                              const float* __restrict__ bias,
                                              float* __restrict__ Cm,
                                              int M, int N, int K, int ldw, int ldc){
  __shared__ float As[16][65];
  __shared__ float Bs[16][64];
  const int t = threadIdx.x;
  const int tx = t & 15, ty = t >> 4;
  const int m0 = blockIdx.y * 64, n0 = blockIdx.x * 64;
  const int akk = t & 15, amm = t >> 4;
  const int bnn = t & 63, bkk = t >> 6;
  float acc[4][4] = {};
  for (int k0 = 0; k0 < K; k0 += 16){
    #pragma unroll
    for (int q = 0; q < 4; q++)
      As[akk][amm + 16*q] = A[(size_t)(m0 + amm + 16*q) * K + k0 + akk];
    #pragma unroll
    for (int q = 0; q < 4; q++)
      Bs[bkk + 4*q][bnn] = W[(size_t)(k0 + bkk + 4*q) * ldw + n0 + bnn];
    __syncthreads();
    #pragma unroll
    for (int kk = 0; kk < 16; kk++){
      float a[4], b[4];
      #pragma unroll
      for (int i = 0; i < 4; i++) a[i] = As[kk][ty*4 + i];
      #pragma unroll
      for (int j = 0; j < 4; j++) b[j] = Bs[kk][tx*4 + j];
      #pragma unroll
      for (int i = 0; i < 4; i++)
        #pragma unroll
        for (int j = 0; j < 4; j++)
          acc[i][j] = fmaf(a[i], b[j], acc[i][j]);
    }
    __syncthreads();
  }
  #pragma unroll
  for (int i = 0; i < 4; i++){
    int m = m0 + ty*4 + i;
    #pragma unroll
    for (int j = 0; j < 4; j++){
      int n = n0 + tx*4 + j;
      float v = acc[i][j];
      if (bias) v += bias[n];
      if (GELU) v = 0.5f * v * (1.0f + erff(v * 0.70710678118654752f));
      size_t idx = (size_t)m * ldc + n;
      if (ACC) Cm[idx] += v; else Cm[idx] = v;
    }
  }
}

// ---------------- bf16 MFMA GEMM: C = [ACC+=] act(A[M,K] @ WtT + bias) ----------------
// Wt is pre-transposed bf16 [N][K]. 128x128 tile, 4 waves, 4x4 16x16 frags/wave.
template<bool GELU, bool ACC, bool ABF, bool OBF>
__global__ __launch_bounds__(256) void mgemm_k(const void* __restrict__ Ap,
                                               const ushort* __restrict__ Wt,
                                               const float* __restrict__ bias,
                                               void* __restrict__ Cp,
                                               int M, int N, int K){
  __shared__ ushort Asm[128][40];
  __shared__ ushort Bsm[128][40];
  const int t = threadIdx.x;
  const int m0 = blockIdx.y * 128, n0 = blockIdx.x * 128;
  const int wave = t >> 6, lane = t & 63;
  const int wrow = wave >> 1, wcol = wave & 1;
  const int lr = lane & 15, ks = lane >> 4;
  const int sr = t >> 3, sc0 = (t & 7) * 4;   // A staging: row group, col start

  f32x4 acc[4][4];
  #pragma unroll
  for (int i = 0; i < 4; i++)
    #pragma unroll
    for (int j = 0; j < 4; j++)
      #pragma unroll
      for (int r = 0; r < 4; r++) acc[i][j][r] = 0.f;

  for (int k0 = 0; k0 < K; k0 += 32){
    // ---- stage A (f32->bf16 inline, or bf16 copy) ----
    if (ABF){
      const ushort* A = (const ushort*)Ap;
      #pragma unroll
      for (int q = 0; q < 4; q++){
        int row = sr + 32*q;
        *reinterpret_cast<ushort4*>(&Asm[row][sc0]) =
          *reinterpret_cast<const ushort4*>(A + (size_t)(m0 + row) * K + k0 + sc0);
      }
    } else {
      const float* A = (const float*)Ap;
      #pragma unroll
      for (int q = 0; q < 4; q++){
        int row = sr + 32*q;
        float4 v = *reinterpret_cast<const float4*>(A + (size_t)(m0 + row) * K + k0 + sc0);
        ushort4 u; u.x = f2b(v.x); u.y = f2b(v.y); u.z = f2b(v.z); u.w = f2b(v.w);
        *reinterpret_cast<ushort4*>(&Asm[row][sc0]) = u;
      }
    }
    // ---- stage B (pre-transposed bf16 weights, coalesced rows) ----
    if (t < 128){
      const ushort* src = Wt + (size_t)(n0 + t) * K + k0;
      #pragma unroll
      for (int q = 0; q < 4; q++)
        *reinterpret_cast<uint4*>(&Bsm[t][q*8]) =
          *reinterpret_cast<const uint4*>(src + q*8);
    }
    __syncthreads();
    // ---- 16 MFMA ----
    s16x8 af[4], bfr[4];
    #pragma unroll
    for (int f = 0; f < 4; f++){
      af[f]  = *reinterpret_cast<const s16x8*>(&Asm[wrow*64 + f*16 + lr][ks*8]);
      bfr[f] = *reinterpret_cast<const s16x8*>(&Bsm[wcol*64 + f*16 + lr][ks*8]);
    }
    #pragma unroll
    for (int i = 0; i < 4; i++)
      #pragma unroll
      for (int j = 0; j < 4; j++)
        acc[i][j] = __builtin_amdgcn_mfma_f32_16x16x32_bf16(af[i], bfr[j], acc[i][j], 0, 0, 0);
    __syncthreads();
  }
  // ---- epilogue ----
  #pragma unroll
  for (int i = 0; i < 4; i++){
    int mb = m0 + wrow*64 + i*16 + ks*4;
    #pragma unroll
    for (int j = 0; j < 4; j++){
      int n = n0 + wcol*64 + j*16 + lr;
      float bv = bias ? bias[n] : 0.0f;
      #pragma unroll
      for (int r = 0; r < 4; r++){
        float v = acc[i][j][r] + bv;
        if (GELU) v = 0.5f * v * (1.0f + erff(v * 0.70710678118654752f));
        size_t idx = (size_t)(mb + r) * N + n;
        if (OBF)      ((ushort*)Cp)[idx] = f2b(v);
        else if (ACC) ((float*)Cp)[idx] += v;
        else          ((float*)Cp)[idx]  = v;
      }
    }
  }
}

// ---------------- weight transpose+convert: Wt[n][k] = bf16(W[k][colOff+n]) ----------------
__global__ __launch_bounds__(256) void tconv_k(const float* __restrict__ W,
                                               ushort* __restrict__ Wt,
                                               int K, int N, int ldw, int colOff){
  __shared__ float tile[32][33];
  int t = threadIdx.x;
  int tx = t & 31, ty = t >> 5;            // 32 x 8
  int k0 = blockIdx.y * 32, n0 = blockIdx.x * 32;
  #pragma unroll
  for (int q = 0; q < 4; q++)
    tile[ty + 8*q][tx] = W[(size_t)(k0 + ty + 8*q) * ldw + colOff + n0 + tx];
  __syncthreads();
  #pragma unroll
  for (int q = 0; q < 4; q++)
    Wt[(size_t)(n0 + ty + 8*q) * K + k0 + tx] = f2b(tile[tx][ty + 8*q]);
}

// ---------------- scores = (q @ k^T) * 0.125 (reads QK buffer, stride 1536) ----------------
__global__ __launch_bounds__(256) void scores_k(const float* __restrict__ qk,
                                                float* __restrict__ sc){
  __shared__ float Qs[16][65];
  __shared__ float Ks[16][65];
  const int t = threadIdx.x, tx = t & 15, ty = t >> 4;
  const int bh = blockIdx.z; const int b = bh / NH, h = bh % NH;
  const int i0 = blockIdx.y * 64, j0 = blockIdx.x * 64;
  const size_t qbase = (size_t)b * LL * QS + (size_t)h * 64;
  const size_t kbase = qbase + 768;
  const int lkk = t & 15, lmm = t >> 4;
  float acc[4][4] = {};
  for (int d0 = 0; d0 < DHD; d0 += 16){
    #pragma unroll
    for (int q = 0; q < 4; q++)
      Qs[lkk][lmm + 16*q] = qk[qbase + (size_t)(i0 + lmm + 16*q) * QS + d0 + lkk];
    #pragma unroll
    for (int q = 0; q < 4; q++)
      Ks[lkk][lmm + 16*q] = qk[kbase + (size_t)(j0 + lmm + 16*q) * QS + d0 + lkk];
    __syncthreads();
    #pragma unroll
    for (int kk = 0; kk < 16; kk++){
      float a[4], b2[4];
      #pragma unroll
      for (int i = 0; i < 4; i++) a[i] = Qs[kk][ty*4 + i];
      #pragma unroll
      for (int j = 0; j < 4; j++) b2[j] = Ks[kk][tx*4 + j];
      #pragma unroll
      for (int i = 0; i < 4; i++)
        #pragma unroll
        for (int j = 0; j < 4; j++)
          acc[i][j] = fmaf(a[i], b2[j], acc[i][j]);
    }
    __syncthreads();
  }
  #pragma unroll
  for (int i = 0; i < 4; i++)
    #pragma unroll
    for (int j = 0; j < 4; j++)
      sc[((size_t)bh * LL + i0 + ty*4 + i) * LL + j0 + tx*4 + j] = acc[i][j] * 0.125f;
}

// ---------------- row softmax over 320, in place ----------------
__global__ __launch_bounds__(256) void softmax_k(float* __restrict__ sc){
  const int lane = threadIdx.x & 63;
  const size_t row = (size_t)blockIdx.x * 4 + (threadIdx.x >> 6);
  float* sr = sc + row * LL;
  float v[5]; float mx = -3.4e38f;
  #pragma unroll
  for (int i = 0; i < 5; i++){ v[i] = sr[lane + 64*i]; mx = fmaxf(mx, v[i]); }
  #pragma unroll
  for (int o = 32; o > 0; o >>= 1) mx = fmaxf(mx, __shfl_xor(mx, o, 64));
  float s = 0.f;
  #pragma unroll
  for (int i = 0; i < 5; i++){ v[i] = expf(v[i] - mx); s += v[i]; }
  #pragma unroll
  for (int o = 32; o > 0; o >>= 1) s += __shfl_xor(s, o, 64);
  float inv = 1.0f / s;
  #pragma unroll
  for (int i = 0; i < 5; i++) sr[lane + 64*i] = v[i] * inv;
}

// ---------------- attn_t (f64 accumulate) ----------------
__global__ __launch_bounds__(256) void attnt_k(const float* __restrict__ probs,
                                               float* __restrict__ at){
  int b = blockIdx.x, j = threadIdx.x;
  double s = 0.0;
  for (int h = 0; h < NH; h++)
    for (int i = 0; i < LT; i++)
      s += (double)probs[(((size_t)b * NH + h) * LL + i) * LL + 64 + j];
  at[b * LSN + j] = (float)(s * (1.0 / 768.0));
}

// ---------------- PV: probs(f32) x V(f32, stride 768) -> pv bf16 ----------------
__global__ __launch_bounds__(256) void pv_k(const float* __restrict__ probs,
                                            const float* __restrict__ vbuf,
                                            ushort* __restrict__ pvb){
  __shared__ float As[16][65];
  __shared__ float Bs[16][64];
  const int t = threadIdx.x, tx = t & 15, ty = t >> 4;
  const int bh = blockIdx.y; const int b = bh / NH, h = bh % NH;
  const int i0 = blockIdx.x * 64;
  const size_t vbase = (size_t)b * LL * 768 + (size_t)h * 64;
  const int akk = t & 15, amm = t >> 4;
  const int bnn = t & 63, bkk = t >> 6;
  const float* Ap = probs + (size_t)bh * LL * LL;
  float acc[4][4] = {};
  for (int k0 = 0; k0 < LL; k0 += 16){
    #pragma unroll
    for (int q = 0; q < 4; q++)
      As[akk][amm + 16*q] = Ap[(size_t)(i0 + amm + 16*q) * LL + k0 + akk];
    #pragma unroll
    for (int q = 0; q < 4; q++)
      Bs[bkk + 4*q][bnn] = vbuf[vbase + (size_t)(k0 + bkk + 4*q) * 768 + bnn];
    __syncthreads();
    #pragma unroll
    for (int kk = 0; kk < 16; kk++){
      float a[4], b2[4];
      #pragma unroll
      for (int i = 0; i < 4; i++) a[i] = As[kk][ty*4 + i];
      #pragma unroll
      for (int j = 0; j < 4; j++) b2[j] = Bs[kk][tx*4 + j];
      #pragma unroll
      for (int i = 0; i < 4; i++)
        #pragma unroll
        for (int j = 0; j < 4; j++)
          acc[i][j] = fmaf(a[i], b2[j], acc[i][j]);
    }
    __syncthreads();
  }
  #pragma unroll
  for (int i = 0; i < 4; i++)
    #pragma unroll
    for (int j = 0; j < 4; j++)
      pvb[((size_t)b * LL + i0 + ty*4 + i) * CC + h*64 + tx*4 + j] = f2b(acc[i][j]);
}

// ---------------- CE: identity init -> rank -> emit ----------------
__global__ __launch_bounds__(256) void init_ord_k(int* __restrict__ ordbuf, int n){
  int i = blockIdx.x * 256 + threadIdx.x;
  if (i < n) ordbuf[i] = i & 255;
}

__global__ __launch_bounds__(256) void ce_rank_k(const float* __restrict__ at,
                                                 int* __restrict__ ordbuf){
  __shared__ float a[256];
  int b = blockIdx.x, t = threadIdx.x;
  a[t] = at[b * LSN + t];
  __syncthreads();
  float mine = a[t];
  int rank = 0;
  for (int k = 0; k < 256; k++){
    float ak = a[k];
    rank += (ak > mine) || (ak == mine && k < t);
  }
  if (rank >= 0 && rank < 256) ordbuf[b * LSN + rank] = t;
}

__global__ __launch_bounds__(256) void ce_emit_k(const int* __restrict__ ordbuf,
                                                 const int* __restrict__ gidx,
                                                 const int* __restrict__ gt,
                                                 float* __restrict__ out_keep,
                                                 float* __restrict__ out_rem,
                                                 float* __restrict__ out_git){
  int b = blockIdx.x, t = threadIdx.x;
  int o = ordbuf[b * LSN + t];
  o = min(max(o, 0), 255);
  int idx = gidx[b * LSN + o];
  if (t < NKEEP) out_keep[b * NKEEP + t] = (float)idx;
  else           out_rem[b * NREM + (t - NKEEP)] = (float)idx;
  if (t < LT)    out_git[b * LT + t] = (float)gt[b * LT + t];
}

// ---------------- gather pruned tokens ----------------
__global__ __launch_bounds__(256) void gather_k(const float* __restrict__ xnew,
                                                const int* __restrict__ ordbuf,
                                                float* __restrict__ x2){
  int row = blockIdx.x;
  int b = row / LP, r = row % LP;
  int o = (r < LT) ? 0 : ordbuf[b * LSN + (r - LT)];
  o = min(max(o, 0), 255);
  int src = (r < LT) ? r : (LT + o);
  const float* s = xnew + ((size_t)b * LL + src) * CC;
  float* d = x2 + (size_t)row * CC;
  for (int i = threadIdx.x; i < CC; i += 256) d[i] = s[i];
}

// ---------------- elementwise ----------------
__global__ void add_k(float* __restrict__ d, const float* __restrict__ s, size_t n){
  size_t i = (size_t)blockIdx.x * 256 + threadIdx.x;
  size_t st = (size_t)gridDim.x * 256;
  for (; i < n; i += st) d[i] += s[i];
}
__global__ void sentinel_k(float* __restrict__ d, float val, int n){
  int i = blockIdx.x * 256 + threadIdx.x;
  if (i < n) d[i] = val;
}

// ======================================================================
extern "C" void kernel_launch(void* const* d_in, const int* in_sizes, int n_in,
                              void* d_out, int out_size, void* d_ws, size_t ws_size,
                              hipStream_t stream) {
  float* out = (float*)d_out;
  float* ws  = (float*)d_ws;

  static const int EXP[26] = {
    7864320, 7864320, 2048, 2048, 8192, 8192, 1,
    768, 768, 1769472, 589824, 768, 768, 768,
    2359296, 3072, 2359296, 768,
    49152, 64, 49152, 768, 49152, 64, 49152, 768 };

  const void* P[26];
  bool ok = false;
  if (n_in == 26){
    bool m = true; int bad = -1;
    for (int i = 0; i < 26; i++) if (in_sizes[i] != EXP[i]){ m = false; bad = i; break; }
    if (m){ for (int i = 0; i < 26; i++) P[i] = d_in[i]; ok = true; }
    else { sentinel_k<<<16, 256, 0, stream>>>(out, 20000.0f + 16.0f*bad, 4096); return; }
  } else if (n_in == 25){
    bool m = true; int bad = -1;
    for (int i = 0; i < 25; i++){
      int j = (i < 6) ? i : i + 1;
      if (in_sizes[i] != EXP[j]){ m = false; bad = i; break; }
    }
    if (m){
      for (int j = 0; j < 26; j++) P[j] = (j == 6) ? nullptr : d_in[(j < 6) ? j : j - 1];
      ok = true;
    } else { sentinel_k<<<16, 256, 0, stream>>>(out, 20000.0f + 16.0f*bad, 4096); return; }
  }
  if (!ok){ sentinel_k<<<16, 256, 0, stream>>>(out, 10000.0f + 8.0f*n_in, 4096); return; }
  if (out_size != 90656768){
    sentinel_k<<<16, 256, 0, stream>>>(out, 60000.0f + (float)(out_size / 1000000), 4096); return;
  }

  const float* x      = (const float*)P[0];
  const float* xi     = (const float*)P[1];
  const int*   gi_t   = (const int*)P[2];
  const int*   gi_ti  = (const int*)P[3];
  const int*   gi_s   = (const int*)P[4];
  const int*   gi_si  = (const int*)P[5];
  const float* n1_g   = (const float*)P[7];
  const float* n1_b   = (const float*)P[8];
  const float* qkv_w  = (const float*)P[9];
  const float* proj_w = (const float*)P[10];
  const float* proj_b = (const float*)P[11];
  const float* n2_g   = (const float*)P[12];
  const float* n2_b   = (const float*)P[13];
  const float* fc1_w  = (const float*)P[14];
  const float* fc1_b  = (const float*)P[15];
  const float* fc2_w  = (const float*)P[16];
  const float* fc2_b  = (const float*)P[17];
  const float* ad1_dw = (const float*)P[18];
  const float* ad1_db = (const float*)P[19];
  const float* ad1_uw = (const float*)P[20];
  const float* ad1_ub = (const float*)P[21];
  const float* ad2_dw = (const float*)P[22];
  const float* ad2_db = (const float*)P[23];
  const float* ad2_uw = (const float*)P[24];
  const float* ad2_ub = (const float*)P[25];

  // output offsets (f32 elements)
  const size_t o_x     = 0;
  const size_t o_git   = 5996544;
  const size_t o_gis   = 5998592;
  const size_t o_rem   = 6004352;
  const size_t o_attn  = 6006784;
  const size_t o_xi    = 45328384;
  const size_t o_giti  = 51324928;
  const size_t o_gisi  = 51326976;
  const size_t o_remi  = 51332736;
  const size_t o_iattn = 51335168;

  // workspace layout (f32 element units) — 282 MB total
  const size_t BLC     = (size_t)NB * LL * CC;            // 7,864,320
  const size_t BPC     = (size_t)NB * LP * CC;            // 5,996,544
  const size_t off_ln  = 0;                               // 2*BLC; B: x2
  const size_t off_qk  = off_ln  + 2*BLC;                 // 15,728,640 (QK f32); B: hid bf16
  const size_t off_v   = off_qk  + (size_t)NB*LL*QS;      // BLC (V f32); B: hid spill
  const size_t off_pv  = off_v   + BLC;                   // BLC/2 (pv bf16)
  const size_t off_xnew= off_pv  + BLC/2;                 // 2*BLC; B: ln2 f32
  const size_t off_l2b = off_xnew+ 2*BLC;                 // BPC (ln2 bf16, both streams)
  const size_t off_mixh= off_l2b + BPC;                   // 2,621,440
  const size_t off_att = off_mixh+ (size_t)2*NB*LL*ADH;
  const size_t off_ord = off_att + 2*(size_t)NB*LSN;
  const size_t off_wts = off_ord + 2*(size_t)NB*LSN;      // bf16 weights
  const size_t total_f = off_wts + 2949120;               // ~70.6M f32 = 282 MB
  if (ws_size < total_f * sizeof(float)){
    sentinel_k<<<16, 256, 0, stream>>>(out, 40000.0f + (float)(ws_size >> 20), 4096);
    return;
  }

  int* ordbuf = (int*)(ws + off_ord);
  ushort* wts = (ushort*)(ws + off_wts);
  ushort* Wt_v    = wts;                 // [768][768]
  ushort* Wt_proj = wts + 589824;        // [768][768]
  ushort* Wt_fc1  = wts + 1179648;       // [3072][768]
  ushort* Wt_fc2  = wts + 3538944;       // [768][3072]
  ushort* pvb  = (ushort*)(ws + off_pv);
  ushort* ln2b = (ushort*)(ws + off_l2b);

  // ---- weight convert+transpose (bf16) ----
  tconv_k<<<dim3(24, 24), 256, 0, stream>>>(qkv_w,  Wt_v,    768, 768,  2304, 1536);
  tconv_k<<<dim3(24, 24), 256, 0, stream>>>(proj_w, Wt_proj, 768, 768,  768,  0);
  tconv_k<<<dim3(96, 24), 256, 0, stream>>>(fc1_w,  Wt_fc1,  768, 3072, 3072, 0);
  tconv_k<<<dim3(24, 96), 256, 0, stream>>>(fc2_w,  Wt_fc2,  3072, 768, 768,  0);

  // ---- Phase A: LN1 + adapter-down ----
  ln_k<<<NB*LL, 256, 0, stream>>>(x,  n1_g, n1_b, ws + off_ln,        nullptr);
  ln_k<<<NB*LL, 256, 0, stream>>>(xi, n1_g, n1_b, ws + off_ln + BLC,  nullptr);
  gemm_k<true,false><<<dim3(1, 320), 256, 0, stream>>>(
      ws + off_ln, ad1_dw, ad1_db, ws + off_mixh, 2*NB*LL, ADH, CC, ADH, ADH);

  // ---- attention per stream ----
  for (int s = 0; s < 2; s++){
    const float* xin  = s ? xi : x;
    const float* ln_s = ws + off_ln + (size_t)s * BLC;
    float* xnew_s     = ws + off_xnew + (size_t)s * BLC;
    float* probs      = out + (s ? o_iattn : o_attn);
    // Q,K in f32 (bit-identical ordering path): cols 0..1535 of qkv_w
    gemm_k<false,false><<<dim3(24, 160), 256, 0, stream>>>(
        ln_s, qkv_w, nullptr, ws + off_qk, NB*LL, QS, CC, 2304, QS);
    // V via bf16 MFMA
    mgemm_k<false,false,false,false><<<dim3(6, 80), 256, 0, stream>>>(
        ln_s, Wt_v, nullptr, ws + off_v, NB*LL, 768, CC);
    scores_k<<<dim3(5, 5, NB*NH), 256, 0, stream>>>(ws + off_qk, probs);
    softmax_k<<<NB*NH*LL/4, 256, 0, stream>>>(probs);
    attnt_k<<<NB, 256, 0, stream>>>(probs, ws + off_att + (size_t)s * NB * LSN);
    pv_k<<<dim3(5, NB*NH), 256, 0, stream>>>(probs, ws + off_v, pvb);
    // proj via MFMA (bf16 A), then residual, then mixer ACC
    mgemm_k<false,false,true,false><<<dim3(6, 80), 256, 0, stream>>>(
        pvb, Wt_proj, proj_b, xnew_s, NB*LL, CC, CC);
    add_k<<<4096, 256, 0, stream>>>(xnew_s, xin, BLC);
    gemm_k<false,true><<<dim3(12, 160), 256, 0, stream>>>(
        ws + off_mixh + (size_t)(1 - s) * NB * LL * ADH, ad1_uw, ad1_ub,
        xnew_s, NB*LL, CC, ADH, CC, CC);
  }

  // ---- CE ----
  init_ord_k<<<(2*NB*LSN + 255)/256, 256, 0, stream>>>(ordbuf, 2*NB*LSN);
  for (int s = 0; s < 2; s++){
    ce_rank_k<<<NB, 256, 0, stream>>>(
        ws + off_att + (size_t)s * NB * LSN, ordbuf + (size_t)s * NB * LSN);
    ce_emit_k<<<NB, 256, 0, stream>>>(
        ordbuf + (size_t)s * NB * LSN,
        s ? gi_si : gi_s, s ? gi_ti : gi_t,
        out + (s ? o_gisi : o_gis), out + (s ? o_remi : o_rem),
        out + (s ? o_giti : o_git));
    gather_k<<<NB*LP, 256, 0, stream>>>(
        ws + off_xnew + (size_t)s * BLC,
        ordbuf + (size_t)s * NB * LSN,
        ws + off_ln + (size_t)s * BPC);
  }

  // ---- Phase B: LN2 (f32 + bf16), adapters, MLP ----
  float* x2    = ws + off_ln;
  float* ln2   = ws + off_xnew;
  float* mixh2 = ws + off_mixh;
  ushort* hidb = (ushort*)(ws + off_qk);   // [7808][3072] bf16 (spills into dead V region)

  ln_k<<<NB*LP, 256, 0, stream>>>(x2,       n2_g, n2_b, ln2,       ln2b);
  ln_k<<<NB*LP, 256, 0, stream>>>(x2 + BPC, n2_g, n2_b, ln2 + BPC, ln2b + BPC);
  gemm_k<true,false><<<dim3(1, 244), 256, 0, stream>>>(
      ln2, ad2_dw, ad2_db, mixh2, 2*NB*LP, ADH, CC, ADH, ADH);

  for (int s = 0; s < 2; s++){
    float* xout = out + (s ? o_xi : o_x);
    // fc1: bf16 A (ln2b), GELU, bf16 out
    mgemm_k<true,false,true,true><<<dim3(24, 61), 256, 0, stream>>>(
        ln2b + (size_t)s * BPC, Wt_fc1, fc1_b, hidb, NB*LP, C4, CC);
    // mixer2 -> xout
    gemm_k<false,false><<<dim3(12, 122), 256, 0, stream>>>(
        mixh2 + (size_t)(1 - s) * NB * LP * ADH, ad2_uw, ad2_ub, xout,
        NB*LP, CC, ADH, CC, CC);
    // += residual
    add_k<<<4096, 256, 0, stream>>>(xout, x2 + (size_t)s * BPC, BPC);
    // fc2: bf16 A (hidb), ACC into xout
    mgemm_k<false,true,true,false><<<dim3(6, 61), 256, 0, stream>>>(
        hidb, Wt_fc2, fc2_b, xout, NB*LP, CC, C4);
  }
}

// Round 7
// 1997.071 us; speedup vs baseline: 2.4023x; 1.1819x over previous
//
#include <hip/hip_runtime.h>
#include <hip/hip_bf16.h>

// Problem constants
#define NB   32
#define LL   320
#define CC   768
#define NH   12
#define DHD  64
#define LT   64
#define LSN  256
#define NKEEP 180
#define NREM  76
#define LP   244
#define ADH  64
#define C4   3072
#define QS   1536    // Q,K buffer row stride

typedef __attribute__((ext_vector_type(8))) short s16x8;
typedef __attribute__((ext_vector_type(4))) float f32x4;

__device__ __forceinline__ ushort f2b(float f){
  union { __hip_bfloat16 h; ushort u; } cv;
  cv.h = __float2bfloat16(f);
  return cv.u;
}

// ---------------- reductions ----------------
__device__ __forceinline__ float blk_sum(float v, float* sh){
  #pragma unroll
  for (int o = 32; o > 0; o >>= 1) v += __shfl_down(v, o, 64);
  int w = threadIdx.x >> 6;
  if ((threadIdx.x & 63) == 0) sh[w] = v;
  __syncthreads();
  float r = sh[0] + sh[1] + sh[2] + sh[3];
  __syncthreads();
  return r;
}

// ---------------- LayerNorm (row = 768), optional bf16 secondary output ----------------
__global__ __launch_bounds__(256) void ln_k(const float* __restrict__ x,
                                            const float* __restrict__ g,
                                            const float* __restrict__ be,
                                            float* __restrict__ y,
                                            ushort* __restrict__ yb){
  __shared__ float sh[4];
  size_t row = blockIdx.x;
  const float* xr = x + row * CC;
  int t = threadIdx.x;
  float v0 = xr[t], v1 = xr[t + 256], v2 = xr[t + 512];
  float m = blk_sum(v0 + v1 + v2, sh) * (1.0f / 768.0f);
  float d0 = v0 - m, d1 = v1 - m, d2 = v2 - m;
  float var = blk_sum(d0*d0 + d1*d1 + d2*d2, sh) * (1.0f / 768.0f);
  float rs = rsqrtf(var + 1e-5f);
  float o0 = d0 * rs * g[t]       + be[t];
  float o1 = d1 * rs * g[t + 256] + be[t + 256];
  float o2 = d2 * rs * g[t + 512] + be[t + 512];
  float* yr = y + row * CC;
  yr[t] = o0; yr[t + 256] = o1; yr[t + 512] = o2;
  if (yb){
    ushort* yr2 = yb + row * CC;
    yr2[t] = f2b(o0); yr2[t + 256] = f2b(o1); yr2[t + 512] = f2b(o2);
  }
}

// ---------------- fast f32 GEMM, bit-identical k-order (QK path) ----------------
// 128x128 tile, 8x8 microtile, K-step 16. A row-major [M][K] (lda=K), W [K][ldw].
__global__ __launch_bounds__(256) void gemm2_k(const float* __restrict__ A,
                                               const float* __restrict__ W,
                                               float* __restrict__ Cm,
                                               int M, int N, int K, int ldw, int ldc){
  __shared__ float As[16][132];
  __shared__ float Bs[16][132];
  const int t = threadIdx.x;
  const int tx = t & 15, ty = t >> 4;
  const int m0 = blockIdx.y * 128, n0 = blockIdx.x * 128;
  float acc[8][8] = {};
  for (int k0 = 0; k0 < K; k0 += 16){
    #pragma unroll
    for (int q = 0; q < 2; q++){
      int idx = t + q*256;
      int m = idx & 127, kq = idx >> 7;
      float4 v = *reinterpret_cast<const float4*>(A + (size_t)(m0+m)*K + k0 + kq*4);
      As[kq*4+0][m] = v.x; As[kq*4+1][m] = v.y;
      As[kq*4+2][m] = v.z; As[kq*4+3][m] = v.w;
    }
    #pragma unroll
    for (int q = 0; q < 2; q++){
      int idx = t + q*256;
      int kr = idx >> 5, nq = idx & 31;
      float4 v = *reinterpret_cast<const float4*>(W + (size_t)(k0+kr)*ldw + n0 + nq*4);
      *reinterpret_cast<float4*>(&Bs[kr][nq*4]) = v;
    }
    __syncthreads();
    #pragma unroll
    for (int kk = 0; kk < 16; kk++){
      float a[8], b[8];
      *reinterpret_cast<float4*>(&a[0]) = *reinterpret_cast<float4*>(&As[kk][ty*8]);
      *reinterpret_cast<float4*>(&a[4]) = *reinterpret_cast<float4*>(&As[kk][ty*8+4]);
      *reinterpret_cast<float4*>(&b[0]) = *reinterpret_cast<float4*>(&Bs[kk][tx*8]);
      *reinterpret_cast<float4*>(&b[4]) = *reinterpret_cast<float4*>(&Bs[kk][tx*8+4]);
      #pragma unroll
      for (int i = 0; i < 8; i++)
        #pragma unroll
        for (int j = 0; j < 8; j++)
          acc[i][j] = fmaf(a[i], b[j], acc[i][j]);
    }
    __syncthreads();
  }
  #pragma unroll
  for (int i = 0; i < 8; i++){
    int m = m0 + ty*8 + i;
    #pragma unroll
    for (int j = 0; j < 8; j++)
      Cm[(size_t)m * ldc + n0 + tx*8 + j] = acc[i][j];
  }
}

// ---------------- bf16 MFMA GEMM: C = [ACC+=] act(A[M,K] @ WtT + bias) ----------------
// Wt pre-transposed bf16 [N][K]. 128x128 tile, 4 waves. N may be < tile (guarded).
template<bool GELU, bool ACC, bool ABF, bool OBF>
__global__ __launch_bounds__(256) void mgemm_k(const void* __restrict__ Ap,
                                               const ushort* __restrict__ Wt,
                                               const float* __restrict__ bias,
                                               void* __restrict__ Cp,
                                               int M, int N, int K){
  __shared__ ushort Asm[128][40];
  __shared__ ushort Bsm[128][40];
  const int t = threadIdx.x;
  const int m0 = blockIdx.y * 128, n0 = blockIdx.x * 128;
  const int wave = t >> 6, lane = t & 63;
  const int wrow = wave >> 1, wcol = wave & 1;
  const int lr = lane & 15, ks = lane >> 4;
  const int sr = t >> 3, sc0 = (t & 7) * 4;

  f32x4 acc[4][4];
  #pragma unroll
  for (int i = 0; i < 4; i++)
    #pragma unroll
    for (int j = 0; j < 4; j++)
      #pragma unroll
      for (int r = 0; r < 4; r++) acc[i][j][r] = 0.f;

  for (int k0 = 0; k0 < K; k0 += 32){
    if (ABF){
      const ushort* A = (const ushort*)Ap;
      #pragma unroll
      for (int q = 0; q < 4; q++){
        int row = sr + 32*q;
        *reinterpret_cast<ushort4*>(&Asm[row][sc0]) =
          *reinterpret_cast<const ushort4*>(A + (size_t)(m0 + row) * K + k0 + sc0);
      }
    } else {
      const float* A = (const float*)Ap;
      #pragma unroll
      for (int q = 0; q < 4; q++){
        int row = sr + 32*q;
        float4 v = *reinterpret_cast<const float4*>(A + (size_t)(m0 + row) * K + k0 + sc0);
        ushort4 u; u.x = f2b(v.x); u.y = f2b(v.y); u.z = f2b(v.z); u.w = f2b(v.w);
        *reinterpret_cast<ushort4*>(&Asm[row][sc0]) = u;
      }
    }
    if (t < 128){
      int nr = n0 + t; if (nr > N - 1) nr = N - 1;
      const ushort* src = Wt + (size_t)nr * K + k0;
      #pragma unroll
      for (int q = 0; q < 4; q++)
        *reinterpret_cast<uint4*>(&Bsm[t][q*8]) =
          *reinterpret_cast<const uint4*>(src + q*8);
    }
    __syncthreads();
    s16x8 af[4], bfr[4];
    #pragma unroll
    for (int f = 0; f < 4; f++){
      af[f]  = *reinterpret_cast<const s16x8*>(&Asm[wrow*64 + f*16 + lr][ks*8]);
      bfr[f] = *reinterpret_cast<const s16x8*>(&Bsm[wcol*64 + f*16 + lr][ks*8]);
    }
    #pragma unroll
    for (int i = 0; i < 4; i++)
      #pragma unroll
      for (int j = 0; j < 4; j++)
        acc[i][j] = __builtin_amdgcn_mfma_f32_16x16x32_bf16(af[i], bfr[j], acc[i][j], 0, 0, 0);
    __syncthreads();
  }
  #pragma unroll
  for (int i = 0; i < 4; i++){
    int mb = m0 + wrow*64 + i*16 + ks*4;
    #pragma unroll
    for (int j = 0; j < 4; j++){
      int n = n0 + wcol*64 + j*16 + lr;
      if (n >= N) continue;
      float bv = bias ? bias[n] : 0.0f;
      #pragma unroll
      for (int r = 0; r < 4; r++){
        float v = acc[i][j][r] + bv;
        if (GELU) v = 0.5f * v * (1.0f + erff(v * 0.70710678118654752f));
        size_t idx = (size_t)(mb + r) * N + n;
        if (OBF)      ((ushort*)Cp)[idx] = f2b(v);
        else if (ACC) ((float*)Cp)[idx] += v;
        else          ((float*)Cp)[idx]  = v;
      }
    }
  }
}

// ---------------- weight transpose+convert: Wt[n][k] = bf16(W[k][colOff+n]) ----------------
__global__ __launch_bounds__(256) void tconv_k(const float* __restrict__ W,
                                               ushort* __restrict__ Wt,
                                               int K, int N, int ldw, int colOff){
  __shared__ float tile[32][33];
  int t = threadIdx.x;
  int tx = t & 31, ty = t >> 5;
  int k0 = blockIdx.y * 32, n0 = blockIdx.x * 32;
  #pragma unroll
  for (int q = 0; q < 4; q++)
    tile[ty + 8*q][tx] = W[(size_t)(k0 + ty + 8*q) * ldw + colOff + n0 + tx];
  __syncthreads();
  #pragma unroll
  for (int q = 0; q < 4; q++)
    Wt[(size_t)(n0 + ty + 8*q) * K + k0 + tx] = f2b(tile[tx][ty + 8*q]);
}

// ---------------- scores = (q @ k^T) * 0.125 (bit-identical path) ----------------
__global__ __launch_bounds__(256) void scores_k(const float* __restrict__ qk,
                                                float* __restrict__ sc){
  __shared__ float Qs[16][65];
  __shared__ float Ks[16][65];
  const int t = threadIdx.x, tx = t & 15, ty = t >> 4;
  const int bh = blockIdx.z; const int b = bh / NH, h = bh % NH;
  const int i0 = blockIdx.y * 64, j0 = blockIdx.x * 64;
  const size_t qbase = (size_t)b * LL * QS + (size_t)h * 64;
  const size_t kbase = qbase + 768;
  const int lkk = t & 15, lmm = t >> 4;
  float acc[4][4] = {};
  for (int d0 = 0; d0 < DHD; d0 += 16){
    #pragma unroll
    for (int q = 0; q < 4; q++)
      Qs[lkk][lmm + 16*q] = qk[qbase + (size_t)(i0 + lmm + 16*q) * QS + d0 + lkk];
    #pragma unroll
    for (int q = 0; q < 4; q++)
      Ks[lkk][lmm + 16*q] = qk[kbase + (size_t)(j0 + lmm + 16*q) * QS + d0 + lkk];
    __syncthreads();
    #pragma unroll
    for (int kk = 0; kk < 16; kk++){
      float a[4], b2[4];
      #pragma unroll
      for (int i = 0; i < 4; i++) a[i] = Qs[kk][ty*4 + i];
      #pragma unroll
      for (int j = 0; j < 4; j++) b2[j] = Ks[kk][tx*4 + j];
      #pragma unroll
      for (int i = 0; i < 4; i++)
        #pragma unroll
        for (int j = 0; j < 4; j++)
          acc[i][j] = fmaf(a[i], b2[j], acc[i][j]);
    }
    __syncthreads();
  }
  #pragma unroll
  for (int i = 0; i < 4; i++)
    #pragma unroll
    for (int j = 0; j < 4; j++)
      sc[((size_t)bh * LL + i0 + ty*4 + i) * LL + j0 + tx*4 + j] = acc[i][j] * 0.125f;
}

// ---------------- row softmax over 320, in place (bit-identical path) ----------------
__global__ __launch_bounds__(256) void softmax_k(float* __restrict__ sc){
  const int lane = threadIdx.x & 63;
  const size_t row = (size_t)blockIdx.x * 4 + (threadIdx.x >> 6);
  float* sr = sc + row * LL;
  float v[5]; float mx = -3.4e38f;
  #pragma unroll
  for (int i = 0; i < 5; i++){ v[i] = sr[lane + 64*i]; mx = fmaxf(mx, v[i]); }
  #pragma unroll
  for (int o = 32; o > 0; o >>= 1) mx = fmaxf(mx, __shfl_xor(mx, o, 64));
  float s = 0.f;
  #pragma unroll
  for (int i = 0; i < 5; i++){ v[i] = expf(v[i] - mx); s += v[i]; }
  #pragma unroll
  for (int o = 32; o > 0; o >>= 1) s += __shfl_xor(s, o, 64);
  float inv = 1.0f / s;
  #pragma unroll
  for (int i = 0; i < 5; i++) sr[lane + 64*i] = v[i] * inv;
}

// ---------------- attn_t (f64 accumulate, bit-identical path) ----------------
__global__ __launch_bounds__(256) void attnt_k(const float* __restrict__ probs,
                                               float* __restrict__ at){
  int b = blockIdx.x, j = threadIdx.x;
  double s = 0.0;
  for (int h = 0; h < NH; h++)
    for (int i = 0; i < LT; i++)
      s += (double)probs[(((size_t)b * NH + h) * LL + i) * LL + 64 + j];
  at[b * LSN + j] = (float)(s * (1.0 / 768.0));
}

// ---------------- PV via MFMA: probs(f32->bf16) x V(bf16) -> pv bf16 ----------------
__global__ __launch_bounds__(256) void pvm_k(const float* __restrict__ probs,
                                             const ushort* __restrict__ vbb,
                                             ushort* __restrict__ pvb){
  __shared__ ushort Pa[64][72];
  __shared__ ushort Vt[64][72];
  const int t = threadIdx.x;
  const int bh = blockIdx.y; const int b = bh / NH, h = bh % NH;
  const int i0 = blockIdx.x * 64;
  const int w = t >> 6, lane = t & 63;
  const int lr = lane & 15, ks = lane >> 4;
  const float* Ap = probs + (size_t)bh * LL * LL;

  f32x4 acc[4];
  #pragma unroll
  for (int n = 0; n < 4; n++)
    #pragma unroll
    for (int r = 0; r < 4; r++) acc[n][r] = 0.f;

  for (int jt = 0; jt < 5; jt++){
    int j0 = jt * 64;
    #pragma unroll
    for (int q = 0; q < 4; q++){
      int idx = t + q*256;
      int i = idx >> 4, jv = idx & 15;
      float4 v = *reinterpret_cast<const float4*>(Ap + (size_t)(i0 + i) * LL + j0 + jv*4);
      ushort4 u; u.x = f2b(v.x); u.y = f2b(v.y); u.z = f2b(v.z); u.w = f2b(v.w);
      *reinterpret_cast<ushort4*>(&Pa[i][jv*4]) = u;
    }
    #pragma unroll
    for (int q = 0; q < 4; q++){
      int idx = t + q*256;
      int j = idx >> 4, dv = idx & 15;
      ushort4 u = *reinterpret_cast<const ushort4*>(
          vbb + (size_t)(b * LL + j0 + j) * 768 + h*64 + dv*4);
      Vt[dv*4+0][j] = u.x; Vt[dv*4+1][j] = u.y;
      Vt[dv*4+2][j] = u.z; Vt[dv*4+3][j] = u.w;
    }
    __syncthreads();
    #pragma unroll
    for (int n = 0; n < 4; n++)
      #pragma unroll
      for (int kt = 0; kt < 2; kt++){
        s16x8 a = *reinterpret_cast<const s16x8*>(&Pa[w*16 + lr][kt*32 + ks*8]);
        s16x8 bb = *reinterpret_cast<const s16x8*>(&Vt[n*16 + lr][kt*32 + ks*8]);
        acc[n] = __builtin_amdgcn_mfma_f32_16x16x32_bf16(a, bb, acc[n], 0, 0, 0);
      }
    __syncthreads();
  }
  #pragma unroll
  for (int n = 0; n < 4; n++)
    #pragma unroll
    for (int r = 0; r < 4; r++){
      int i = w*16 + ks*4 + r;
      int d = n*16 + lr;
      pvb[(size_t)(b * LL + i0 + i) * 768 + h*64 + d] = f2b(acc[n][r]);
    }
}

// ---------------- CE: identity init -> rank -> emit ----------------
__global__ __launch_bounds__(256) void init_ord_k(int* __restrict__ ordbuf, int n){
  int i = blockIdx.x * 256 + threadIdx.x;
  if (i < n) ordbuf[i] = i & 255;
}

__global__ __launch_bounds__(256) void ce_rank_k(const float* __restrict__ at,
                                                 int* __restrict__ ordbuf){
  __shared__ float a[256];
  int b = blockIdx.x, t = threadIdx.x;
  a[t] = at[b * LSN + t];
  __syncthreads();
  float mine = a[t];
  int rank = 0;
  for (int k = 0; k < 256; k++){
    float ak = a[k];
    rank += (ak > mine) || (ak == mine && k < t);
  }
  if (rank >= 0 && rank < 256) ordbuf[b * LSN + rank] = t;
}

__global__ __launch_bounds__(256) void ce_emit_k(const int* __restrict__ ordbuf,
                                                 const int* __restrict__ gidx,
                                                 const int* __restrict__ gt,
                                                 float* __restrict__ out_keep,
                                                 float* __restrict__ out_rem,
                                                 float* __restrict__ out_git){
  int b = blockIdx.x, t = threadIdx.x;
  int o = ordbuf[b * LSN + t];
  o = min(max(o, 0), 255);
  int idx = gidx[b * LSN + o];
  if (t < NKEEP) out_keep[b * NKEEP + t] = (float)idx;
  else           out_rem[b * NREM + (t - NKEEP)] = (float)idx;
  if (t < LT)    out_git[b * LT + t] = (float)gt[b * LT + t];
}

// ---------------- gather pruned tokens ----------------
__global__ __launch_bounds__(256) void gather_k(const float* __restrict__ xnew,
                                                const int* __restrict__ ordbuf,
                                                float* __restrict__ x2){
  int row = blockIdx.x;
  int b = row / LP, r = row % LP;
  int o = (r < LT) ? 0 : ordbuf[b * LSN + (r - LT)];
  o = min(max(o, 0), 255);
  int src = (r < LT) ? r : (LT + o);
  const float* s = xnew + ((size_t)b * LL + src) * CC;
  float* d = x2 + (size_t)row * CC;
  for (int i = threadIdx.x; i < CC; i += 256) d[i] = s[i];
}

// ---------------- elementwise ----------------
__global__ void add_k(float* __restrict__ d, const float* __restrict__ s, size_t n){
  size_t i = (size_t)blockIdx.x * 256 + threadIdx.x;
  size_t st = (size_t)gridDim.x * 256;
  for (; i < n; i += st) d[i] += s[i];
}
__global__ void sentinel_k(float* __restrict__ d, float val, int n){
  int i = blockIdx.x * 256 + threadIdx.x;
  if (i < n) d[i] = val;
}

// ======================================================================
extern "C" void kernel_launch(void* const* d_in, const int* in_sizes, int n_in,
                              void* d_out, int out_size, void* d_ws, size_t ws_size,
                              hipStream_t stream) {
  float* out = (float*)d_out;
  float* ws  = (float*)d_ws;

  static const int EXP[26] = {
    7864320, 7864320, 2048, 2048, 8192, 8192, 1,
    768, 768, 1769472, 589824, 768, 768, 768,
    2359296, 3072, 2359296, 768,
    49152, 64, 49152, 768, 49152, 64, 49152, 768 };

  const void* P[26];
  bool ok = false;
  if (n_in == 26){
    bool m = true; int bad = -1;
    for (int i = 0; i < 26; i++) if (in_sizes[i] != EXP[i]){ m = false; bad = i; break; }
    if (m){ for (int i = 0; i < 26; i++) P[i] = d_in[i]; ok = true; }
    else { sentinel_k<<<16, 256, 0, stream>>>(out, 20000.0f + 16.0f*bad, 4096); return; }
  } else if (n_in == 25){
    bool m = true; int bad = -1;
    for (int i = 0; i < 25; i++){
      int j = (i < 6) ? i : i + 1;
      if (in_sizes[i] != EXP[j]){ m = false; bad = i; break; }
    }
    if (m){
      for (int j = 0; j < 26; j++) P[j] = (j == 6) ? nullptr : d_in[(j < 6) ? j : j - 1];
      ok = true;
    } else { sentinel_k<<<16, 256, 0, stream>>>(out, 20000.0f + 16.0f*bad, 4096); return; }
  }
  if (!ok){ sentinel_k<<<16, 256, 0, stream>>>(out, 10000.0f + 8.0f*n_in, 4096); return; }
  if (out_size != 90656768){
    sentinel_k<<<16, 256, 0, stream>>>(out, 60000.0f + (float)(out_size / 1000000), 4096); return;
  }

  const float* x      = (const float*)P[0];
  const float* xi     = (const float*)P[1];
  const int*   gi_t   = (const int*)P[2];
  const int*   gi_ti  = (const int*)P[3];
  const int*   gi_s   = (const int*)P[4];
  const int*   gi_si  = (const int*)P[5];
  const float* n1_g   = (const float*)P[7];
  const float* n1_b   = (const float*)P[8];
  const float* qkv_w  = (const float*)P[9];
  const float* proj_w = (const float*)P[10];
  const float* proj_b = (const float*)P[11];
  const float* n2_g   = (const float*)P[12];
  const float* n2_b   = (const float*)P[13];
  const float* fc1_w  = (const float*)P[14];
  const float* fc1_b  = (const float*)P[15];
  const float* fc2_w  = (const float*)P[16];
  const float* fc2_b  = (const float*)P[17];
  const float* ad1_dw = (const float*)P[18];
  const float* ad1_db = (const float*)P[19];
  const float* ad1_uw = (const float*)P[20];
  const float* ad1_ub = (const float*)P[21];
  const float* ad2_dw = (const float*)P[22];
  const float* ad2_db = (const float*)P[23];
  const float* ad2_uw = (const float*)P[24];
  const float* ad2_ub = (const float*)P[25];

  // output offsets (f32 elements)
  const size_t o_x     = 0;
  const size_t o_git   = 5996544;
  const size_t o_gis   = 5998592;
  const size_t o_rem   = 6004352;
  const size_t o_attn  = 6006784;
  const size_t o_xi    = 45328384;
  const size_t o_giti  = 51324928;
  const size_t o_gisi  = 51326976;
  const size_t o_remi  = 51332736;
  const size_t o_iattn = 51335168;

  // workspace layout (f32 units) — 275 MB
  const size_t BLC     = (size_t)NB * LL * CC;            // 7,864,320
  const size_t BPC     = (size_t)NB * LP * CC;            // 5,996,544
  const size_t off_ln  = 0;                               // 2*BLC (LN1 f32; B: x2)
  const size_t off_l1b = off_ln  + 2*BLC;                 // BLC (LN1 bf16, 2 streams)
  const size_t off_qk  = off_l1b + BLC;                   // 15,728,640 (QK f32; pvb alias; B: hidb)
  const size_t off_vb  = off_qk  + (size_t)NB*LL*QS;      // BLC/2 (V bf16)
  const size_t off_xnew= off_vb  + BLC/2;                 // 2*BLC (xnew f32; B: ln2 f32)
  const size_t off_l2b = off_xnew+ 2*BLC;                 // BPC (ln2 bf16, 2 streams)
  const size_t off_mixh= off_l2b + BPC;                   // 655,360 (mixh bf16, 2 streams)
  const size_t off_att = off_mixh+ 655360;
  const size_t off_ord = off_att + 2*(size_t)NB*LSN;
  const size_t off_wts = off_ord + 2*(size_t)NB*LSN;
  const size_t total_f = off_wts + 3047424;               // 68,714,496 f32 = 275 MB
  if (ws_size < total_f * sizeof(float)){
    sentinel_k<<<16, 256, 0, stream>>>(out, 40000.0f + (float)(ws_size >> 20), 4096);
    return;
  }

  int* ordbuf = (int*)(ws + off_ord);
  ushort* wts = (ushort*)(ws + off_wts);
  ushort* Wt_v    = wts;                 // [768][768]
  ushort* Wt_proj = wts + 589824;        // [768][768]
  ushort* Wt_fc1  = wts + 1179648;       // [3072][768]
  ushort* Wt_fc2  = wts + 3538944;       // [768][3072]
  ushort* Wt_a1d  = wts + 5898240;       // [64][768]
  ushort* Wt_a1u  = wts + 5947392;       // [768][64]
  ushort* Wt_a2d  = wts + 5996544;       // [64][768]
  ushort* Wt_a2u  = wts + 6045696;       // [768][64]
  ushort* ln1b  = (ushort*)(ws + off_l1b);
  ushort* vbb   = (ushort*)(ws + off_vb);
  ushort* pvb   = (ushort*)(ws + off_qk);   // aliases dead QK region (per-stream)
  ushort* ln2b  = (ushort*)(ws + off_l2b);
  ushort* mixhb = (ushort*)(ws + off_mixh);

  // ---- weight convert+transpose (bf16) ----
  tconv_k<<<dim3(24, 24), 256, 0, stream>>>(qkv_w,  Wt_v,    768, 768,  2304, 1536);
  tconv_k<<<dim3(24, 24), 256, 0, stream>>>(proj_w, Wt_proj, 768, 768,  768,  0);
  tconv_k<<<dim3(96, 24), 256, 0, stream>>>(fc1_w,  Wt_fc1,  768, 3072, 3072, 0);
  tconv_k<<<dim3(24, 96), 256, 0, stream>>>(fc2_w,  Wt_fc2,  3072, 768, 768,  0);
  tconv_k<<<dim3(2,  24), 256, 0, stream>>>(ad1_dw, Wt_a1d,  768, 64,   64,   0);
  tconv_k<<<dim3(24, 2 ), 256, 0, stream>>>(ad1_uw, Wt_a1u,  64,  768,  768,  0);
  tconv_k<<<dim3(2,  24), 256, 0, stream>>>(ad2_dw, Wt_a2d,  768, 64,   64,   0);
  tconv_k<<<dim3(24, 2 ), 256, 0, stream>>>(ad2_uw, Wt_a2u,  64,  768,  768,  0);

  // ---- Phase A: LN1 (f32 + bf16) + adapter-down (MFMA, both streams) ----
  ln_k<<<NB*LL, 256, 0, stream>>>(x,  n1_g, n1_b, ws + off_ln,       ln1b);
  ln_k<<<NB*LL, 256, 0, stream>>>(xi, n1_g, n1_b, ws + off_ln + BLC, ln1b + BLC);
  mgemm_k<true,false,true,true><<<dim3(1, 160), 256, 0, stream>>>(
      ln1b, Wt_a1d, ad1_db, mixhb, 2*NB*LL, ADH, CC);

  // ---- attention per stream ----
  for (int s = 0; s < 2; s++){
    const float* xin  = s ? xi : x;
    const float* ln_s = ws + off_ln + (size_t)s * BLC;
    float* xnew_s     = ws + off_xnew + (size_t)s * BLC;
    float* probs      = out + (s ? o_iattn : o_attn);
    // Q,K f32 — bit-identical ordering path
    gemm2_k<<<dim3(12, 80), 256, 0, stream>>>(
        ln_s, qkv_w, ws + off_qk, NB*LL, QS, CC, 2304, QS);
    // V via MFMA (bf16 in, bf16 out)
    mgemm_k<false,false,true,true><<<dim3(6, 80), 256, 0, stream>>>(
        ln1b + (size_t)s * BLC, Wt_v, nullptr, vbb, NB*LL, 768, CC);
    scores_k<<<dim3(5, 5, NB*NH), 256, 0, stream>>>(ws + off_qk, probs);
    softmax_k<<<NB*NH*LL/4, 256, 0, stream>>>(probs);
    attnt_k<<<NB, 256, 0, stream>>>(probs, ws + off_att + (size_t)s * NB * LSN);
    // PV via MFMA (writes into dead QK region)
    pvm_k<<<dim3(5, NB*NH), 256, 0, stream>>>(probs, vbb, pvb);
    // proj via MFMA, then residual, then mixer ACC
    mgemm_k<false,false,true,false><<<dim3(6, 80), 256, 0, stream>>>(
        pvb, Wt_proj, proj_b, xnew_s, NB*LL, CC, CC);
    add_k<<<4096, 256, 0, stream>>>(xnew_s, xin, BLC);
    mgemm_k<false,true,true,false><<<dim3(6, 80), 256, 0, stream>>>(
        mixhb + (size_t)(1 - s) * NB * LL * ADH, Wt_a1u, ad1_ub,
        xnew_s, NB*LL, CC, ADH);
  }

  // ---- CE ----
  init_ord_k<<<(2*NB*LSN + 255)/256, 256, 0, stream>>>(ordbuf, 2*NB*LSN);
  for (int s = 0; s < 2; s++){
    ce_rank_k<<<NB, 256, 0, stream>>>(
        ws + off_att + (size_t)s * NB * LSN, ordbuf + (size_t)s * NB * LSN);
    ce_emit_k<<<NB, 256, 0, stream>>>(
        ordbuf + (size_t)s * NB * LSN,
        s ? gi_si : gi_s, s ? gi_ti : gi_t,
        out + (s ? o_gisi : o_gis), out + (s ? o_remi : o_rem),
        out + (s ? o_giti : o_git));
    gather_k<<<NB*LP, 256, 0, stream>>>(
        ws + off_xnew + (size_t)s * BLC,
        ordbuf + (size_t)s * NB * LSN,
        ws + off_ln + (size_t)s * BPC);
  }

  // ---- Phase B: LN2 (f32 + bf16), adapters + MLP all-MFMA ----
  float* x2    = ws + off_ln;
  float* ln2   = ws + off_xnew;
  ushort* hidb   = (ushort*)(ws + off_qk);   // [7808][3072] bf16
  ushort* mixh2b = mixhb;                    // reuse

  ln_k<<<NB*LP, 256, 0, stream>>>(x2,       n2_g, n2_b, ln2,       ln2b);
  ln_k<<<NB*LP, 256, 0, stream>>>(x2 + BPC, n2_g, n2_b, ln2 + BPC, ln2b + BPC);
  mgemm_k<true,false,true,true><<<dim3(1, 122), 256, 0, stream>>>(
      ln2b, Wt_a2d, ad2_db, mixh2b, 2*NB*LP, ADH, CC);

  for (int s = 0; s < 2; s++){
    float* xout = out + (s ? o_xi : o_x);
    // fc1: bf16 A, GELU, bf16 out
    mgemm_k<true,false,true,true><<<dim3(24, 61), 256, 0, stream>>>(
        ln2b + (size_t)s * BPC, Wt_fc1, fc1_b, hidb, NB*LP, C4, CC);
    // mixer2 (overwrite xout)
    mgemm_k<false,false,true,false><<<dim3(6, 61), 256, 0, stream>>>(
        mixh2b + (size_t)(1 - s) * NB * LP * ADH, Wt_a2u, ad2_ub, xout, NB*LP, CC, ADH);
    // += residual
    add_k<<<4096, 256, 0, stream>>>(xout, x2 + (size_t)s * BPC, BPC);
    // fc2: ACC into xout
    mgemm_k<false,true,true,false><<<dim3(6, 61), 256, 0, stream>>>(
        hidb, Wt_fc2, fc2_b, xout, NB*LP, CC, C4);
  }
}

// Round 8
// 1961.307 us; speedup vs baseline: 2.4461x; 1.0182x over previous
//
#include <hip/hip_runtime.h>
#include <hip/hip_bf16.h>

// Problem constants
#define NB   32
#define LL   320
#define CC   768
#define NH   12
#define DHD  64
#define LT   64
#define LSN  256
#define NKEEP 180
#define NREM  76
#define LP   244
#define ADH  64
#define C4   3072
#define QS   1536    // Q,K buffer row stride

typedef __attribute__((ext_vector_type(8))) short s16x8;
typedef __attribute__((ext_vector_type(4))) float f32x4;

__device__ __forceinline__ ushort f2b(float f){
  union { __hip_bfloat16 h; ushort u; } cv;
  cv.h = __float2bfloat16(f);
  return cv.u;
}

// ---------------- reductions ----------------
__device__ __forceinline__ float blk_sum(float v, float* sh){
  #pragma unroll
  for (int o = 32; o > 0; o >>= 1) v += __shfl_down(v, o, 64);
  int w = threadIdx.x >> 6;
  if ((threadIdx.x & 63) == 0) sh[w] = v;
  __syncthreads();
  float r = sh[0] + sh[1] + sh[2] + sh[3];
  __syncthreads();
  return r;
}

// ---------------- LayerNorm (row = 768), optional bf16 secondary output ----------------
__global__ __launch_bounds__(256) void ln_k(const float* __restrict__ x,
                                            const float* __restrict__ g,
                                            const float* __restrict__ be,
                                            float* __restrict__ y,
                                            ushort* __restrict__ yb){
  __shared__ float sh[4];
  size_t row = blockIdx.x;
  const float* xr = x + row * CC;
  int t = threadIdx.x;
  float v0 = xr[t], v1 = xr[t + 256], v2 = xr[t + 512];
  float m = blk_sum(v0 + v1 + v2, sh) * (1.0f / 768.0f);
  float d0 = v0 - m, d1 = v1 - m, d2 = v2 - m;
  float var = blk_sum(d0*d0 + d1*d1 + d2*d2, sh) * (1.0f / 768.0f);
  float rs = rsqrtf(var + 1e-5f);
  float o0 = d0 * rs * g[t]       + be[t];
  float o1 = d1 * rs * g[t + 256] + be[t + 256];
  float o2 = d2 * rs * g[t + 512] + be[t + 512];
  float* yr = y + row * CC;
  yr[t] = o0; yr[t + 256] = o1; yr[t + 512] = o2;
  if (yb){
    ushort* yr2 = yb + row * CC;
    yr2[t] = f2b(o0); yr2[t + 256] = f2b(o1); yr2[t + 512] = f2b(o2);
  }
}

// ---------------- fast f32 GEMM, bit-identical k-order (QK path) ----------------
// 128x128 tile, 8x8 microtile in split quadrants (conflict-free LDS reads).
__global__ __launch_bounds__(256) void gemm2_k(const float* __restrict__ A,
                                               const float* __restrict__ W,
                                               float* __restrict__ Cm,
                                               int M, int N, int K, int ldw, int ldc){
  __shared__ float As[16][132];
  __shared__ float Bs[16][132];
  const int t = threadIdx.x;
  const int tx = t & 15, ty = t >> 4;
  const int m0 = blockIdx.y * 128, n0 = blockIdx.x * 128;
  float acc[8][8] = {};
  for (int k0 = 0; k0 < K; k0 += 16){
    #pragma unroll
    for (int q = 0; q < 2; q++){
      int idx = t + q*256;
      int m = idx & 127, kq = idx >> 7;
      float4 v = *reinterpret_cast<const float4*>(A + (size_t)(m0+m)*K + k0 + kq*4);
      As[kq*4+0][m] = v.x; As[kq*4+1][m] = v.y;
      As[kq*4+2][m] = v.z; As[kq*4+3][m] = v.w;
    }
    #pragma unroll
    for (int q = 0; q < 2; q++){
      int idx = t + q*256;
      int kr = idx >> 5, nq = idx & 31;
      float4 v = *reinterpret_cast<const float4*>(W + (size_t)(k0+kr)*ldw + n0 + nq*4);
      *reinterpret_cast<float4*>(&Bs[kr][nq*4]) = v;
    }
    __syncthreads();
    #pragma unroll
    for (int kk = 0; kk < 16; kk++){
      float a[8], b[8];
      *reinterpret_cast<float4*>(&a[0]) = *reinterpret_cast<float4*>(&As[kk][ty*4]);
      *reinterpret_cast<float4*>(&a[4]) = *reinterpret_cast<float4*>(&As[kk][64 + ty*4]);
      *reinterpret_cast<float4*>(&b[0]) = *reinterpret_cast<float4*>(&Bs[kk][tx*4]);
      *reinterpret_cast<float4*>(&b[4]) = *reinterpret_cast<float4*>(&Bs[kk][64 + tx*4]);
      #pragma unroll
      for (int i = 0; i < 8; i++)
        #pragma unroll
        for (int j = 0; j < 8; j++)
          acc[i][j] = fmaf(a[i], b[j], acc[i][j]);
    }
    __syncthreads();
  }
  #pragma unroll
  for (int i = 0; i < 8; i++){
    int m = m0 + ty*4 + (i & 3) + (i >> 2) * 64;
    #pragma unroll
    for (int j = 0; j < 8; j++){
      int n = n0 + tx*4 + (j & 3) + (j >> 2) * 64;
      Cm[(size_t)m * ldc + n] = acc[i][j];
    }
  }
}

// ---------------- bf16 MFMA GEMM: C = [ACC+=] act(A[M,K] @ WtT + bias) ----------------
template<bool GELU, bool ACC, bool ABF, bool OBF>
__global__ __launch_bounds__(256) void mgemm_k(const void* __restrict__ Ap,
                                               const ushort* __restrict__ Wt,
                                               const float* __restrict__ bias,
                                               void* __restrict__ Cp,
                                               int M, int N, int K){
  __shared__ ushort Asm[128][40];
  __shared__ ushort Bsm[128][40];
  const int t = threadIdx.x;
  const int m0 = blockIdx.y * 128, n0 = blockIdx.x * 128;
  const int wave = t >> 6, lane = t & 63;
  const int wrow = wave >> 1, wcol = wave & 1;
  const int lr = lane & 15, ks = lane >> 4;
  const int sr = t >> 3, sc0 = (t & 7) * 4;

  f32x4 acc[4][4];
  #pragma unroll
  for (int i = 0; i < 4; i++)
    #pragma unroll
    for (int j = 0; j < 4; j++)
      #pragma unroll
      for (int r = 0; r < 4; r++) acc[i][j][r] = 0.f;

  for (int k0 = 0; k0 < K; k0 += 32){
    if (ABF){
      const ushort* A = (const ushort*)Ap;
      #pragma unroll
      for (int q = 0; q < 4; q++){
        int row = sr + 32*q;
        *reinterpret_cast<ushort4*>(&Asm[row][sc0]) =
          *reinterpret_cast<const ushort4*>(A + (size_t)(m0 + row) * K + k0 + sc0);
      }
    } else {
      const float* A = (const float*)Ap;
      #pragma unroll
      for (int q = 0; q < 4; q++){
        int row = sr + 32*q;
        float4 v = *reinterpret_cast<const float4*>(A + (size_t)(m0 + row) * K + k0 + sc0);
        ushort4 u; u.x = f2b(v.x); u.y = f2b(v.y); u.z = f2b(v.z); u.w = f2b(v.w);
        *reinterpret_cast<ushort4*>(&Asm[row][sc0]) = u;
      }
    }
    if (t < 128){
      int nr = n0 + t; if (nr > N - 1) nr = N - 1;
      const ushort* src = Wt + (size_t)nr * K + k0;
      #pragma unroll
      for (int q = 0; q < 4; q++)
        *reinterpret_cast<uint4*>(&Bsm[t][q*8]) =
          *reinterpret_cast<const uint4*>(src + q*8);
    }
    __syncthreads();
    s16x8 af[4], bfr[4];
    #pragma unroll
    for (int f = 0; f < 4; f++){
      af[f]  = *reinterpret_cast<const s16x8*>(&Asm[wrow*64 + f*16 + lr][ks*8]);
      bfr[f] = *reinterpret_cast<const s16x8*>(&Bsm[wcol*64 + f*16 + lr][ks*8]);
    }
    #pragma unroll
    for (int i = 0; i < 4; i++)
      #pragma unroll
      for (int j = 0; j < 4; j++)
        acc[i][j] = __builtin_amdgcn_mfma_f32_16x16x32_bf16(af[i], bfr[j], acc[i][j], 0, 0, 0);
    __syncthreads();
  }
  #pragma unroll
  for (int i = 0; i < 4; i++){
    int mb = m0 + wrow*64 + i*16 + ks*4;
    #pragma unroll
    for (int j = 0; j < 4; j++){
      int n = n0 + wcol*64 + j*16 + lr;
      if (n >= N) continue;
      float bv = bias ? bias[n] : 0.0f;
      #pragma unroll
      for (int r = 0; r < 4; r++){
        float v = acc[i][j][r] + bv;
        if (GELU) v = 0.5f * v * (1.0f + erff(v * 0.70710678118654752f));
        size_t idx = (size_t)(mb + r) * N + n;
        if (OBF)      ((ushort*)Cp)[idx] = f2b(v);
        else if (ACC) ((float*)Cp)[idx] += v;
        else          ((float*)Cp)[idx]  = v;
      }
    }
  }
}

// ---------------- weight transpose+convert ----------------
__global__ __launch_bounds__(256) void tconv_k(const float* __restrict__ W,
                                               ushort* __restrict__ Wt,
                                               int K, int N, int ldw, int colOff){
  __shared__ float tile[32][33];
  int t = threadIdx.x;
  int tx = t & 31, ty = t >> 5;
  int k0 = blockIdx.y * 32, n0 = blockIdx.x * 32;
  #pragma unroll
  for (int q = 0; q < 4; q++)
    tile[ty + 8*q][tx] = W[(size_t)(k0 + ty + 8*q) * ldw + colOff + n0 + tx];
  __syncthreads();
  #pragma unroll
  for (int q = 0; q < 4; q++)
    Wt[(size_t)(n0 + ty + 8*q) * K + k0 + tx] = f2b(tile[tx][ty + 8*q]);
}

// ---------------- scores = (q @ k^T) * 0.125 (bit-identical path) ----------------
__global__ __launch_bounds__(256) void scores_k(const float* __restrict__ qk,
                                                float* __restrict__ sc){
  __shared__ float Qs[16][65];
  __shared__ float Ks[16][65];
  const int t = threadIdx.x, tx = t & 15, ty = t >> 4;
  const int bh = blockIdx.z; const int b = bh / NH, h = bh % NH;
  const int i0 = blockIdx.y * 64, j0 = blockIdx.x * 64;
  const size_t qbase = (size_t)b * LL * QS + (size_t)h * 64;
  const size_t kbase = qbase + 768;
  const int lkk = t & 15, lmm = t >> 4;
  float acc[4][4] = {};
  for (int d0 = 0; d0 < DHD; d0 += 16){
    #pragma unroll
    for (int q = 0; q < 4; q++)
      Qs[lkk][lmm + 16*q] = qk[qbase + (size_t)(i0 + lmm + 16*q) * QS + d0 + lkk];
    #pragma unroll
    for (int q = 0; q < 4; q++)
      Ks[lkk][lmm + 16*q] = qk[kbase + (size_t)(j0 + lmm + 16*q) * QS + d0 + lkk];
    __syncthreads();
    #pragma unroll
    for (int kk = 0; kk < 16; kk++){
      float a[4], b2[4];
      #pragma unroll
      for (int i = 0; i < 4; i++) a[i] = Qs[kk][ty*4 + i];
      #pragma unroll
      for (int j = 0; j < 4; j++) b2[j] = Ks[kk][tx*4 + j];
      #pragma unroll
      for (int i = 0; i < 4; i++)
        #pragma unroll
        for (int j = 0; j < 4; j++)
          acc[i][j] = fmaf(a[i], b2[j], acc[i][j]);
    }
    __syncthreads();
  }
  #pragma unroll
  for (int i = 0; i < 4; i++)
    #pragma unroll
    for (int j = 0; j < 4; j++)
      sc[((size_t)bh * LL + i0 + ty*4 + i) * LL + j0 + tx*4 + j] = acc[i][j] * 0.125f;
}

// ---------------- row softmax over 320, in place (bit-identical path) ----------------
__global__ __launch_bounds__(256) void softmax_k(float* __restrict__ sc){
  const int lane = threadIdx.x & 63;
  const size_t row = (size_t)blockIdx.x * 4 + (threadIdx.x >> 6);
  float* sr = sc + row * LL;
  float v[5]; float mx = -3.4e38f;
  #pragma unroll
  for (int i = 0; i < 5; i++){ v[i] = sr[lane + 64*i]; mx = fmaxf(mx, v[i]); }
  #pragma unroll
  for (int o = 32; o > 0; o >>= 1) mx = fmaxf(mx, __shfl_xor(mx, o, 64));
  float s = 0.f;
  #pragma unroll
  for (int i = 0; i < 5; i++){ v[i] = expf(v[i] - mx); s += v[i]; }
  #pragma unroll
  for (int o = 32; o > 0; o >>= 1) s += __shfl_xor(s, o, 64);
  float inv = 1.0f / s;
  #pragma unroll
  for (int i = 0; i < 5; i++) sr[lane + 64*i] = v[i] * inv;
}

// ---------------- attn_t (f64 accumulate, bit-identical path) ----------------
__global__ __launch_bounds__(256) void attnt_k(const float* __restrict__ probs,
                                               float* __restrict__ at){
  int b = blockIdx.x, j = threadIdx.x;
  double s = 0.0;
  for (int h = 0; h < NH; h++)
    for (int i = 0; i < LT; i++)
      s += (double)probs[(((size_t)b * NH + h) * LL + i) * LL + 64 + j];
  at[b * LSN + j] = (float)(s * (1.0 / 768.0));
}

// ---------------- PV via MFMA ----------------
__global__ __launch_bounds__(256) void pvm_k(const float* __restrict__ probs,
                                             const ushort* __restrict__ vbb,
                                             ushort* __restrict__ pvb){
  __shared__ ushort Pa[64][72];
  __shared__ ushort Vt[64][72];
  const int t = threadIdx.x;
  const int bh = blockIdx.y; const int b = bh / NH, h = bh % NH;
  const int i0 = blockIdx.x * 64;
  const int w = t >> 6, lane = t & 63;
  const int lr = lane & 15, ks = lane >> 4;
  const float* Ap = probs + (size_t)bh * LL * LL;

  f32x4 acc[4];
  #pragma unroll
  for (int n = 0; n < 4; n++)
    #pragma unroll
    for (int r = 0; r < 4; r++) acc[n][r] = 0.f;

  for (int jt = 0; jt < 5; jt++){
    int j0 = jt * 64;
    #pragma unroll
    for (int q = 0; q < 4; q++){
      int idx = t + q*256;
      int i = idx >> 4, jv = idx & 15;
      float4 v = *reinterpret_cast<const float4*>(Ap + (size_t)(i0 + i) * LL + j0 + jv*4);
      ushort4 u; u.x = f2b(v.x); u.y = f2b(v.y); u.z = f2b(v.z); u.w = f2b(v.w);
      *reinterpret_cast<ushort4*>(&Pa[i][jv*4]) = u;
    }
    #pragma unroll
    for (int q = 0; q < 4; q++){
      int idx = t + q*256;
      int j = idx >> 4, dv = idx & 15;
      ushort4 u = *reinterpret_cast<const ushort4*>(
          vbb + (size_t)(b * LL + j0 + j) * 768 + h*64 + dv*4);
      Vt[dv*4+0][j] = u.x; Vt[dv*4+1][j] = u.y;
      Vt[dv*4+2][j] = u.z; Vt[dv*4+3][j] = u.w;
    }
    __syncthreads();
    #pragma unroll
    for (int n = 0; n < 4; n++)
      #pragma unroll
      for (int kt = 0; kt < 2; kt++){
        s16x8 a = *reinterpret_cast<const s16x8*>(&Pa[w*16 + lr][kt*32 + ks*8]);
        s16x8 bb = *reinterpret_cast<const s16x8*>(&Vt[n*16 + lr][kt*32 + ks*8]);
        acc[n] = __builtin_amdgcn_mfma_f32_16x16x32_bf16(a, bb, acc[n], 0, 0, 0);
      }
    __syncthreads();
  }
  #pragma unroll
  for (int n = 0; n < 4; n++)
    #pragma unroll
    for (int r = 0; r < 4; r++){
      int i = w*16 + ks*4 + r;
      int d = n*16 + lr;
      pvb[(size_t)(b * LL + i0 + i) * 768 + h*64 + d] = f2b(acc[n][r]);
    }
}

// ---------------- CE ----------------
__global__ __launch_bounds__(256) void init_ord_k(int* __restrict__ ordbuf, int n){
  int i = blockIdx.x * 256 + threadIdx.x;
  if (i < n) ordbuf[i] = i & 255;
}

__global__ __launch_bounds__(256) void ce_rank_k(const float* __restrict__ at,
                                                 int* __restrict__ ordbuf){
  __shared__ float a[256];
  int b = blockIdx.x, t = threadIdx.x;
  a[t] = at[b * LSN + t];
  __syncthreads();
  float mine = a[t];
  int rank = 0;
  for (int k = 0; k < 256; k++){
    float ak = a[k];
    rank += (ak > mine) || (ak == mine && k < t);
  }
  if (rank >= 0 && rank < 256) ordbuf[b * LSN + rank] = t;
}

__global__ __launch_bounds__(256) void ce_emit_k(const int* __restrict__ ordbuf,
                                                 const int* __restrict__ gidx,
                                                 const int* __restrict__ gt,
                                                 float* __restrict__ out_keep,
                                                 float* __restrict__ out_rem,
                                                 float* __restrict__ out_git){
  int b = blockIdx.x, t = threadIdx.x;
  int o = ordbuf[b * LSN + t];
  o = min(max(o, 0), 255);
  int idx = gidx[b * LSN + o];
  if (t < NKEEP) out_keep[b * NKEEP + t] = (float)idx;
  else           out_rem[b * NREM + (t - NKEEP)] = (float)idx;
  if (t < LT)    out_git[b * LT + t] = (float)gt[b * LT + t];
}

// ---------------- gather ----------------
__global__ __launch_bounds__(256) void gather_k(const float* __restrict__ xnew,
                                                const int* __restrict__ ordbuf,
                                                float* __restrict__ x2){
  int row = blockIdx.x;
  int b = row / LP, r = row % LP;
  int o = (r < LT) ? 0 : ordbuf[b * LSN + (r - LT)];
  o = min(max(o, 0), 255);
  int src = (r < LT) ? r : (LT + o);
  const float* s = xnew + ((size_t)b * LL + src) * CC;
  float* d = x2 + (size_t)row * CC;
  for (int i = threadIdx.x; i < CC; i += 256) d[i] = s[i];
}

// ---------------- elementwise ----------------
__global__ void add_k(float* __restrict__ d, const float* __restrict__ s, size_t n){
  size_t i = (size_t)blockIdx.x * 256 + threadIdx.x;
  size_t st = (size_t)gridDim.x * 256;
  for (; i < n; i += st) d[i] += s[i];
}
// d[0..n) += (i<half ? s0[i] : s1[i-half])
__global__ void add2_k(float* __restrict__ d, const float* __restrict__ s0,
                       const float* __restrict__ s1, size_t half){
  size_t i = (size_t)blockIdx.x * 256 + threadIdx.x;
  size_t st = (size_t)gridDim.x * 256;
  for (; i < 2*half; i += st) d[i] += (i < half) ? s0[i] : s1[i - half];
}
__global__ void sentinel_k(float* __restrict__ d, float val, int n){
  int i = blockIdx.x * 256 + threadIdx.x;
  if (i < n) d[i] = val;
}

// ======================================================================
extern "C" void kernel_launch(void* const* d_in, const int* in_sizes, int n_in,
                              void* d_out, int out_size, void* d_ws, size_t ws_size,
                              hipStream_t stream) {
  float* out = (float*)d_out;
  float* ws  = (float*)d_ws;

  static const int EXP[26] = {
    7864320, 7864320, 2048, 2048, 8192, 8192, 1,
    768, 768, 1769472, 589824, 768, 768, 768,
    2359296, 3072, 2359296, 768,
    49152, 64, 49152, 768, 49152, 64, 49152, 768 };

  const void* P[26];
  bool ok = false;
  if (n_in == 26){
    bool m = true; int bad = -1;
    for (int i = 0; i < 26; i++) if (in_sizes[i] != EXP[i]){ m = false; bad = i; break; }
    if (m){ for (int i = 0; i < 26; i++) P[i] = d_in[i]; ok = true; }
    else { sentinel_k<<<16, 256, 0, stream>>>(out, 20000.0f + 16.0f*bad, 4096); return; }
  } else if (n_in == 25){
    bool m = true; int bad = -1;
    for (int i = 0; i < 25; i++){
      int j = (i < 6) ? i : i + 1;
      if (in_sizes[i] != EXP[j]){ m = false; bad = i; break; }
    }
    if (m){
      for (int j = 0; j < 26; j++) P[j] = (j == 6) ? nullptr : d_in[(j < 6) ? j : j - 1];
      ok = true;
    } else { sentinel_k<<<16, 256, 0, stream>>>(out, 20000.0f + 16.0f*bad, 4096); return; }
  }
  if (!ok){ sentinel_k<<<16, 256, 0, stream>>>(out, 10000.0f + 8.0f*n_in, 4096); return; }
  if (out_size != 90656768){
    sentinel_k<<<16, 256, 0, stream>>>(out, 60000.0f + (float)(out_size / 1000000), 4096); return;
  }

  const float* x      = (const float*)P[0];
  const float* xi     = (const float*)P[1];
  const int*   gi_t   = (const int*)P[2];
  const int*   gi_ti  = (const int*)P[3];
  const int*   gi_s   = (const int*)P[4];
  const int*   gi_si  = (const int*)P[5];
  const float* n1_g   = (const float*)P[7];
  const float* n1_b   = (const float*)P[8];
  const float* qkv_w  = (const float*)P[9];
  const float* proj_w = (const float*)P[10];
  const float* proj_b = (const float*)P[11];
  const float* n2_g   = (const float*)P[12];
  const float* n2_b   = (const float*)P[13];
  const float* fc1_w  = (const float*)P[14];
  const float* fc1_b  = (const float*)P[15];
  const float* fc2_w  = (const float*)P[16];
  const float* fc2_b  = (const float*)P[17];
  const float* ad1_dw = (const float*)P[18];
  const float* ad1_db = (const float*)P[19];
  const float* ad1_uw = (const float*)P[20];
  const float* ad1_ub = (const float*)P[21];
  const float* ad2_dw = (const float*)P[22];
  const float* ad2_db = (const float*)P[23];
  const float* ad2_uw = (const float*)P[24];
  const float* ad2_ub = (const float*)P[25];

  // output offsets (f32 elements)
  const size_t o_x     = 0;
  const size_t o_git   = 5996544;
  const size_t o_gis   = 5998592;
  const size_t o_rem   = 6004352;
  const size_t o_attn  = 6006784;
  const size_t o_xi    = 45328384;
  const size_t o_giti  = 51324928;
  const size_t o_gisi  = 51326976;
  const size_t o_remi  = 51332736;
  const size_t o_iattn = 51335168;

  // workspace layout (f32 units) — 354 MB
  const size_t BLC     = (size_t)NB * LL * CC;            // 7,864,320
  const size_t BPC     = (size_t)NB * LP * CC;            // 5,996,544
  const size_t off_ln  = 0;                               // 2*BLC (ln1 f32 both; B: x2 both)
  const size_t off_l1b = off_ln  + 2*BLC;                 // BLC (ln1 bf16 both)
  const size_t off_qk  = off_l1b + BLC;                   // 2*NB*LL*QS (QK both; A: pvb; B: hidb)
  const size_t off_vb  = off_qk  + 2*(size_t)NB*LL*QS;    // BLC (vbb both, bf16)
  const size_t off_xnew= off_vb  + BLC;                   // 2*BLC (xnew both; B: ln2 f32 both)
  const size_t off_l2b = off_xnew+ 2*BLC;                 // BPC (ln2 bf16 both)
  const size_t off_mixh= off_l2b + BPC;                   // 655,360 (mixh bf16 both)
  const size_t off_att = off_mixh+ 655360;
  const size_t off_ord = off_att + 2*(size_t)NB*LSN;
  const size_t off_wts = off_ord + 2*(size_t)NB*LSN;
  const size_t total_f = off_wts + 3047424;               // 88,375,296 f32 = 354 MB
  if (ws_size < total_f * sizeof(float)){
    sentinel_k<<<16, 256, 0, stream>>>(out, 40000.0f + (float)(ws_size >> 20), 4096);
    return;
  }

  int* ordbuf = (int*)(ws + off_ord);
  ushort* wts = (ushort*)(ws + off_wts);
  ushort* Wt_v    = wts;                 // [768][768]
  ushort* Wt_proj = wts + 589824;        // [768][768]
  ushort* Wt_fc1  = wts + 1179648;       // [3072][768]
  ushort* Wt_fc2  = wts + 3538944;       // [768][3072]
  ushort* Wt_a1d  = wts + 5898240;       // [64][768]
  ushort* Wt_a1u  = wts + 5947392;       // [768][64]
  ushort* Wt_a2d  = wts + 5996544;       // [64][768]
  ushort* Wt_a2u  = wts + 6045696;       // [768][64]
  ushort* ln1b  = (ushort*)(ws + off_l1b);
  ushort* vbb   = (ushort*)(ws + off_vb);
  ushort* pvb   = (ushort*)(ws + off_qk);   // aliases dead QK region
  ushort* ln2b  = (ushort*)(ws + off_l2b);
  ushort* mixhb = (ushort*)(ws + off_mixh);

  // ---- weight convert+transpose (bf16) ----
  tconv_k<<<dim3(24, 24), 256, 0, stream>>>(qkv_w,  Wt_v,    768, 768,  2304, 1536);
  tconv_k<<<dim3(24, 24), 256, 0, stream>>>(proj_w, Wt_proj, 768, 768,  768,  0);
  tconv_k<<<dim3(96, 24), 256, 0, stream>>>(fc1_w,  Wt_fc1,  768, 3072, 3072, 0);
  tconv_k<<<dim3(24, 96), 256, 0, stream>>>(fc2_w,  Wt_fc2,  3072, 768, 768,  0);
  tconv_k<<<dim3(2,  24), 256, 0, stream>>>(ad1_dw, Wt_a1d,  768, 64,   64,   0);
  tconv_k<<<dim3(24, 2 ), 256, 0, stream>>>(ad1_uw, Wt_a1u,  64,  768,  768,  0);
  tconv_k<<<dim3(2,  24), 256, 0, stream>>>(ad2_dw, Wt_a2d,  768, 64,   64,   0);
  tconv_k<<<dim3(24, 2 ), 256, 0, stream>>>(ad2_uw, Wt_a2u,  64,  768,  768,  0);

  // ---- Phase A: LN1 + adapter-down + batched QK/V ----
  ln_k<<<NB*LL, 256, 0, stream>>>(x,  n1_g, n1_b, ws + off_ln,       ln1b);
  ln_k<<<NB*LL, 256, 0, stream>>>(xi, n1_g, n1_b, ws + off_ln + BLC, ln1b + BLC);
  mgemm_k<true,false,true,true><<<dim3(1, 160), 256, 0, stream>>>(
      ln1b, Wt_a1d, ad1_db, mixhb, 2*NB*LL, ADH, CC);
  // QK both streams (bit-identical f32 path), M = 20480
  gemm2_k<<<dim3(12, 160), 256, 0, stream>>>(
      ws + off_ln, qkv_w, ws + off_qk, 2*NB*LL, QS, CC, 2304, QS);
  // V both streams via MFMA
  mgemm_k<false,false,true,true><<<dim3(6, 160), 256, 0, stream>>>(
      ln1b, Wt_v, nullptr, vbb, 2*NB*LL, 768, CC);

  // ---- per-stream attention (probs in d_out) ----
  for (int s = 0; s < 2; s++){
    float* probs = out + (s ? o_iattn : o_attn);
    const float* qk_s = ws + off_qk + (size_t)s * NB * LL * QS;
    scores_k<<<dim3(5, 5, NB*NH), 256, 0, stream>>>(qk_s, probs);
    softmax_k<<<NB*NH*LL/4, 256, 0, stream>>>(probs);
    attnt_k<<<NB, 256, 0, stream>>>(probs, ws + off_att + (size_t)s * NB * LSN);
    pvm_k<<<dim3(5, NB*NH), 256, 0, stream>>>(
        probs, vbb + (size_t)s * NB * LL * 768, pvb + (size_t)s * NB * LL * 768);
  }
  // proj both streams (pvb contiguous) -> xnew
  mgemm_k<false,false,true,false><<<dim3(6, 160), 256, 0, stream>>>(
      pvb, Wt_proj, proj_b, ws + off_xnew, 2*NB*LL, CC, CC);
  // residuals both streams
  add2_k<<<4096, 256, 0, stream>>>(ws + off_xnew, x, xi, BLC);
  // cross mixers (per stream, ACC)
  for (int s = 0; s < 2; s++)
    mgemm_k<false,true,true,false><<<dim3(6, 80), 256, 0, stream>>>(
        mixhb + (size_t)(1 - s) * NB * LL * ADH, Wt_a1u, ad1_ub,
        ws + off_xnew + (size_t)s * BLC, NB*LL, CC, ADH);

  // ---- CE ----
  init_ord_k<<<(2*NB*LSN + 255)/256, 256, 0, stream>>>(ordbuf, 2*NB*LSN);
  for (int s = 0; s < 2; s++){
    ce_rank_k<<<NB, 256, 0, stream>>>(
        ws + off_att + (size_t)s * NB * LSN, ordbuf + (size_t)s * NB * LSN);
    ce_emit_k<<<NB, 256, 0, stream>>>(
        ordbuf + (size_t)s * NB * LSN,
        s ? gi_si : gi_s, s ? gi_ti : gi_t,
        out + (s ? o_gisi : o_gis), out + (s ? o_remi : o_rem),
        out + (s ? o_giti : o_git));
    gather_k<<<NB*LP, 256, 0, stream>>>(
        ws + off_xnew + (size_t)s * BLC,
        ordbuf + (size_t)s * NB * LSN,
        ws + off_ln + (size_t)s * BPC);
  }

  // ---- Phase B: LN2 batched, adapters + MLP ----
  float* x2    = ws + off_ln;
  float* ln2   = ws + off_xnew;
  ushort* hidb   = (ushort*)(ws + off_qk);   // [15616][3072] bf16
  ushort* mixh2b = mixhb;

  ln_k<<<2*NB*LP, 256, 0, stream>>>(x2, n2_g, n2_b, ln2, ln2b);
  mgemm_k<true,false,true,true><<<dim3(1, 122), 256, 0, stream>>>(
      ln2b, Wt_a2d, ad2_db, mixh2b, 2*NB*LP, ADH, CC);
  // fc1 both streams: [15616][768] -> [15616][3072] bf16
  mgemm_k<true,false,true,true><<<dim3(24, 122), 256, 0, stream>>>(
      ln2b, Wt_fc1, fc1_b, hidb, 2*NB*LP, C4, CC);

  for (int s = 0; s < 2; s++){
    float* xout = out + (s ? o_xi : o_x);
    // mixer2 (overwrite xout)
    mgemm_k<false,false,true,false><<<dim3(6, 61), 256, 0, stream>>>(
        mixh2b + (size_t)(1 - s) * NB * LP * ADH, Wt_a2u, ad2_ub, xout, NB*LP, CC, ADH);
    // += residual
    add_k<<<4096, 256, 0, stream>>>(xout, x2 + (size_t)s * BPC, BPC);
    // fc2: ACC into xout
    mgemm_k<false,true,true,false><<<dim3(6, 61), 256, 0, stream>>>(
        hidb + (size_t)s * NB * LP * C4, Wt_fc2, fc2_b, xout, NB*LP, CC, C4);
  }
}

// Round 9
// 1776.108 us; speedup vs baseline: 2.7012x; 1.1043x over previous
//
#include <hip/hip_runtime.h>
#include <hip/hip_bf16.h>

// Problem constants
#define NB   32
#define LL   320
#define CC   768
#define NH   12
#define DHD  64
#define LT   64
#define LSN  256
#define NKEEP 180
#define NREM  76
#define LP   244
#define ADH  64
#define C4   3072

typedef __attribute__((ext_vector_type(8))) short s16x8;
typedef __attribute__((ext_vector_type(4))) float f32x4;

__device__ __forceinline__ ushort f2b(float f){
  union { __hip_bfloat16 h; ushort u; } cv;
  cv.h = __float2bfloat16(f);
  return cv.u;
}

// ---------------- reductions ----------------
__device__ __forceinline__ float blk_sum(float v, float* sh){
  #pragma unroll
  for (int o = 32; o > 0; o >>= 1) v += __shfl_down(v, o, 64);
  int w = threadIdx.x >> 6;
  if ((threadIdx.x & 63) == 0) sh[w] = v;
  __syncthreads();
  float r = sh[0] + sh[1] + sh[2] + sh[3];
  __syncthreads();
  return r;
}

// ---------------- LayerNorm (row = 768), optional bf16 secondary output ----------------
__global__ __launch_bounds__(256) void ln_k(const float* __restrict__ x,
                                            const float* __restrict__ g,
                                            const float* __restrict__ be,
                                            float* __restrict__ y,
                                            ushort* __restrict__ yb){
  __shared__ float sh[4];
  size_t row = blockIdx.x;
  const float* xr = x + row * CC;
  int t = threadIdx.x;
  float v0 = xr[t], v1 = xr[t + 256], v2 = xr[t + 512];
  float m = blk_sum(v0 + v1 + v2, sh) * (1.0f / 768.0f);
  float d0 = v0 - m, d1 = v1 - m, d2 = v2 - m;
  float var = blk_sum(d0*d0 + d1*d1 + d2*d2, sh) * (1.0f / 768.0f);
  float rs = rsqrtf(var + 1e-5f);
  float o0 = d0 * rs * g[t]       + be[t];
  float o1 = d1 * rs * g[t + 256] + be[t + 256];
  float o2 = d2 * rs * g[t + 512] + be[t + 512];
  float* yr = y + row * CC;
  yr[t] = o0; yr[t + 256] = o1; yr[t + 512] = o2;
  if (yb){
    ushort* yr2 = yb + row * CC;
    yr2[t] = f2b(o0); yr2[t + 256] = f2b(o1); yr2[t + 512] = f2b(o2);
  }
}

// ---------------- copy template LN rows: lnt[(sb)*64+i] = ln1[sb*320+i] ----------------
__global__ __launch_bounds__(256) void copyt_k(const float* __restrict__ ln1,
                                               float* __restrict__ lnt){
  int row = blockIdx.x;                 // (s*NB+b)*64 + i
  int sb = row >> 6, i = row & 63;
  const float* src = ln1 + ((size_t)sb * LL + i) * CC;
  float* dst = lnt + (size_t)row * CC;
  int t = threadIdx.x;
  dst[t] = src[t]; dst[t+256] = src[t+256]; dst[t+512] = src[t+512];
}

// ---------------- fast f32 GEMM, bit-identical k-order; optional bf16 mirror ----------------
// 128x128 tile, 8x8 microtile split quadrants (conflict-free).
__global__ __launch_bounds__(256) void gemm2_k(const float* __restrict__ A,
                                               const float* __restrict__ W,
                                               float* __restrict__ Cm,
                                               ushort* __restrict__ Cb,
                                               int M, int N, int K, int ldw, int ldc){
  __shared__ float As[16][132];
  __shared__ float Bs[16][132];
  const int t = threadIdx.x;
  const int tx = t & 15, ty = t >> 4;
  const int m0 = blockIdx.y * 128, n0 = blockIdx.x * 128;
  float acc[8][8] = {};
  for (int k0 = 0; k0 < K; k0 += 16){
    #pragma unroll
    for (int q = 0; q < 2; q++){
      int idx = t + q*256;
      int m = idx & 127, kq = idx >> 7;
      float4 v = *reinterpret_cast<const float4*>(A + (size_t)(m0+m)*K + k0 + kq*4);
      As[kq*4+0][m] = v.x; As[kq*4+1][m] = v.y;
      As[kq*4+2][m] = v.z; As[kq*4+3][m] = v.w;
    }
    #pragma unroll
    for (int q = 0; q < 2; q++){
      int idx = t + q*256;
      int kr = idx >> 5, nq = idx & 31;
      float4 v = *reinterpret_cast<const float4*>(W + (size_t)(k0+kr)*ldw + n0 + nq*4);
      *reinterpret_cast<float4*>(&Bs[kr][nq*4]) = v;
    }
    __syncthreads();
    #pragma unroll
    for (int kk = 0; kk < 16; kk++){
      float a[8], b[8];
      *reinterpret_cast<float4*>(&a[0]) = *reinterpret_cast<float4*>(&As[kk][ty*4]);
      *reinterpret_cast<float4*>(&a[4]) = *reinterpret_cast<float4*>(&As[kk][64 + ty*4]);
      *reinterpret_cast<float4*>(&b[0]) = *reinterpret_cast<float4*>(&Bs[kk][tx*4]);
      *reinterpret_cast<float4*>(&b[4]) = *reinterpret_cast<float4*>(&Bs[kk][64 + tx*4]);
      #pragma unroll
      for (int i = 0; i < 8; i++)
        #pragma unroll
        for (int j = 0; j < 8; j++)
          acc[i][j] = fmaf(a[i], b[j], acc[i][j]);
    }
    __syncthreads();
  }
  #pragma unroll
  for (int i = 0; i < 8; i++){
    int m = m0 + ty*4 + (i & 3) + (i >> 2) * 64;
    #pragma unroll
    for (int j = 0; j < 8; j++){
      int n = n0 + tx*4 + (j & 3) + (j >> 2) * 64;
      float v = acc[i][j];
      Cm[(size_t)m * ldc + n] = v;
      if (Cb) Cb[(size_t)m * ldc + n] = f2b(v);
    }
  }
}

// ---------------- bf16 MFMA GEMM ----------------
template<bool GELU, bool ACC, bool ABF, bool OBF>
__global__ __launch_bounds__(256) void mgemm_k(const void* __restrict__ Ap,
                                               const ushort* __restrict__ Wt,
                                               const float* __restrict__ bias,
                                               void* __restrict__ Cp,
                                               int M, int N, int K){
  __shared__ ushort Asm[128][40];
  __shared__ ushort Bsm[128][40];
  const int t = threadIdx.x;
  const int m0 = blockIdx.y * 128, n0 = blockIdx.x * 128;
  const int wave = t >> 6, lane = t & 63;
  const int wrow = wave >> 1, wcol = wave & 1;
  const int lr = lane & 15, ks = lane >> 4;
  const int sr = t >> 3, sc0 = (t & 7) * 4;

  f32x4 acc[4][4];
  #pragma unroll
  for (int i = 0; i < 4; i++)
    #pragma unroll
    for (int j = 0; j < 4; j++)
      #pragma unroll
      for (int r = 0; r < 4; r++) acc[i][j][r] = 0.f;

  for (int k0 = 0; k0 < K; k0 += 32){
    if (ABF){
      const ushort* A = (const ushort*)Ap;
      #pragma unroll
      for (int q = 0; q < 4; q++){
        int row = sr + 32*q;
        *reinterpret_cast<ushort4*>(&Asm[row][sc0]) =
          *reinterpret_cast<const ushort4*>(A + (size_t)(m0 + row) * K + k0 + sc0);
      }
    } else {
      const float* A = (const float*)Ap;
      #pragma unroll
      for (int q = 0; q < 4; q++){
        int row = sr + 32*q;
        float4 v = *reinterpret_cast<const float4*>(A + (size_t)(m0 + row) * K + k0 + sc0);
        ushort4 u; u.x = f2b(v.x); u.y = f2b(v.y); u.z = f2b(v.z); u.w = f2b(v.w);
        *reinterpret_cast<ushort4*>(&Asm[row][sc0]) = u;
      }
    }
    if (t < 128){
      int nr = n0 + t; if (nr > N - 1) nr = N - 1;
      const ushort* src = Wt + (size_t)nr * K + k0;
      #pragma unroll
      for (int q = 0; q < 4; q++)
        *reinterpret_cast<uint4*>(&Bsm[t][q*8]) =
          *reinterpret_cast<const uint4*>(src + q*8);
    }
    __syncthreads();
    s16x8 af[4], bfr[4];
    #pragma unroll
    for (int f = 0; f < 4; f++){
      af[f]  = *reinterpret_cast<const s16x8*>(&Asm[wrow*64 + f*16 + lr][ks*8]);
      bfr[f] = *reinterpret_cast<const s16x8*>(&Bsm[wcol*64 + f*16 + lr][ks*8]);
    }
    #pragma unroll
    for (int i = 0; i < 4; i++)
      #pragma unroll
      for (int j = 0; j < 4; j++)
        acc[i][j] = __builtin_amdgcn_mfma_f32_16x16x32_bf16(af[i], bfr[j], acc[i][j], 0, 0, 0);
    __syncthreads();
  }
  #pragma unroll
  for (int i = 0; i < 4; i++){
    int mb = m0 + wrow*64 + i*16 + ks*4;
    #pragma unroll
    for (int j = 0; j < 4; j++){
      int n = n0 + wcol*64 + j*16 + lr;
      if (n >= N) continue;
      float bv = bias ? bias[n] : 0.0f;
      #pragma unroll
      for (int r = 0; r < 4; r++){
        float v = acc[i][j][r] + bv;
        if (GELU) v = 0.5f * v * (1.0f + erff(v * 0.70710678118654752f));
        size_t idx = (size_t)(mb + r) * N + n;
        if (OBF)      ((ushort*)Cp)[idx] = f2b(v);
        else if (ACC) ((float*)Cp)[idx] += v;
        else          ((float*)Cp)[idx]  = v;
      }
    }
  }
}

// ---------------- weight transpose+convert ----------------
__global__ __launch_bounds__(256) void tconv_k(const float* __restrict__ W,
                                               ushort* __restrict__ Wt,
                                               int K, int N, int ldw, int colOff){
  __shared__ float tile[32][33];
  int t = threadIdx.x;
  int tx = t & 31, ty = t >> 5;
  int k0 = blockIdx.y * 32, n0 = blockIdx.x * 32;
  #pragma unroll
  for (int q = 0; q < 4; q++)
    tile[ty + 8*q][tx] = W[(size_t)(k0 + ty + 8*q) * ldw + colOff + n0 + tx];
  __syncthreads();
  #pragma unroll
  for (int q = 0; q < 4; q++)
    Wt[(size_t)(n0 + ty + 8*q) * K + k0 + tx] = f2b(tile[tx][ty + 8*q]);
}

// ---------------- template scores (bit-identical f32): rows < 64 ----------------
// qt: [2*NB*64][768] f32 (template Q), kf: [2*NB*320][768] f32 (K)
__global__ __launch_bounds__(256) void scorest_k(const float* __restrict__ qt,
                                                 const float* __restrict__ kf,
                                                 float* __restrict__ sc){
  __shared__ float Qs[16][65];
  __shared__ float Ks[16][65];
  const int t = threadIdx.x, tx = t & 15, ty = t >> 4;
  const int bh = blockIdx.z; const int b = bh / NH, h = bh % NH;
  const int j0 = blockIdx.x * 64;
  const size_t qbase = (size_t)b * 64 * CC + (size_t)h * 64;
  const size_t kbase = (size_t)b * LL * CC + (size_t)h * 64;
  const int lkk = t & 15, lmm = t >> 4;
  float acc[4][4] = {};
  for (int d0 = 0; d0 < DHD; d0 += 16){
    #pragma unroll
    for (int q = 0; q < 4; q++)
      Qs[lkk][lmm + 16*q] = qt[qbase + (size_t)(lmm + 16*q) * CC + d0 + lkk];
    #pragma unroll
    for (int q = 0; q < 4; q++)
      Ks[lkk][lmm + 16*q] = kf[kbase + (size_t)(j0 + lmm + 16*q) * CC + d0 + lkk];
    __syncthreads();
    #pragma unroll
    for (int kk = 0; kk < 16; kk++){
      float a[4], b2[4];
      #pragma unroll
      for (int i = 0; i < 4; i++) a[i] = Qs[kk][ty*4 + i];
      #pragma unroll
      for (int j = 0; j < 4; j++) b2[j] = Ks[kk][tx*4 + j];
      #pragma unroll
      for (int i = 0; i < 4; i++)
        #pragma unroll
        for (int j = 0; j < 4; j++)
          acc[i][j] = fmaf(a[i], b2[j], acc[i][j]);
    }
    __syncthreads();
  }
  #pragma unroll
  for (int i = 0; i < 4; i++)
    #pragma unroll
    for (int j = 0; j < 4; j++)
      sc[((size_t)bh * LL + ty*4 + i) * LL + j0 + tx*4 + j] = acc[i][j] * 0.125f;
}

// ---------------- spatial scores via MFMA: rows 64..319 ----------------
// qb, kb: [NB*320][768] bf16 per stream
__global__ __launch_bounds__(256) void sqk_k(const ushort* __restrict__ qb,
                                             const ushort* __restrict__ kb,
                                             float* __restrict__ sc){
  __shared__ ushort Qs[64][72];
  __shared__ ushort Ks[64][72];
  const int t = threadIdx.x;
  const int it = blockIdx.x, jt = blockIdx.y, bh = blockIdx.z;
  const int b = bh / NH, h = bh % NH;
  const int qrow0 = b * LL + 64 + it * 64;
  const int krow0 = b * LL + jt * 64;
  const int w = t >> 6, lane = t & 63;
  const int lr = lane & 15, ks = lane >> 4;

  #pragma unroll
  for (int q = 0; q < 4; q++){
    int idx = t + q*256;
    int row = idx >> 4, dv = idx & 15;
    *reinterpret_cast<ushort4*>(&Qs[row][dv*4]) =
      *reinterpret_cast<const ushort4*>(qb + (size_t)(qrow0 + row) * CC + h*64 + dv*4);
    *reinterpret_cast<ushort4*>(&Ks[row][dv*4]) =
      *reinterpret_cast<const ushort4*>(kb + (size_t)(krow0 + row) * CC + h*64 + dv*4);
  }
  __syncthreads();

  f32x4 acc[4];
  #pragma unroll
  for (int n = 0; n < 4; n++)
    #pragma unroll
    for (int r = 0; r < 4; r++) acc[n][r] = 0.f;
  #pragma unroll
  for (int n = 0; n < 4; n++)
    #pragma unroll
    for (int kt = 0; kt < 2; kt++){
      s16x8 a  = *reinterpret_cast<const s16x8*>(&Qs[w*16 + lr][kt*32 + ks*8]);
      s16x8 bb = *reinterpret_cast<const s16x8*>(&Ks[n*16 + lr][kt*32 + ks*8]);
      acc[n] = __builtin_amdgcn_mfma_f32_16x16x32_bf16(a, bb, acc[n], 0, 0, 0);
    }
  #pragma unroll
  for (int n = 0; n < 4; n++)
    #pragma unroll
    for (int r = 0; r < 4; r++){
      int i = 64 + it*64 + w*16 + ks*4 + r;
      int j = jt*64 + n*16 + lr;
      sc[((size_t)bh * LL + i) * LL + j] = acc[n][r] * 0.125f;
    }
}

// ---------------- row softmax over 320, in place (bit-identical for rows<64) ----------------
__global__ __launch_bounds__(256) void softmax_k(float* __restrict__ sc){
  const int lane = threadIdx.x & 63;
  const size_t row = (size_t)blockIdx.x * 4 + (threadIdx.x >> 6);
  float* sr = sc + row * LL;
  float v[5]; float mx = -3.4e38f;
  #pragma unroll
  for (int i = 0; i < 5; i++){ v[i] = sr[lane + 64*i]; mx = fmaxf(mx, v[i]); }
  #pragma unroll
  for (int o = 32; o > 0; o >>= 1) mx = fmaxf(mx, __shfl_xor(mx, o, 64));
  float s = 0.f;
  #pragma unroll
  for (int i = 0; i < 5; i++){ v[i] = expf(v[i] - mx); s += v[i]; }
  #pragma unroll
  for (int o = 32; o > 0; o >>= 1) s += __shfl_xor(s, o, 64);
  float inv = 1.0f / s;
  #pragma unroll
  for (int i = 0; i < 5; i++) sr[lane + 64*i] = v[i] * inv;
}

// ---------------- attn_t two-stage (f64) ----------------
__global__ __launch_bounds__(256) void attnt1_k(const float* __restrict__ probs,
                                                double* __restrict__ pp){
  int bh = blockIdx.x, j = threadIdx.x;
  double s = 0.0;
  for (int i = 0; i < LT; i++)
    s += (double)probs[((size_t)bh * LL + i) * LL + 64 + j];
  pp[(size_t)bh * LSN + j] = s;
}
__global__ __launch_bounds__(256) void attnt2_k(const double* __restrict__ pp,
                                                float* __restrict__ at){
  int b = blockIdx.x, j = threadIdx.x;
  double s = 0.0;
  for (int h = 0; h < NH; h++)
    s += pp[((size_t)b * NH + h) * LSN + j];
  at[b * LSN + j] = (float)(s * (1.0 / 768.0));
}

// ---------------- PV via MFMA ----------------
__global__ __launch_bounds__(256) void pvm_k(const float* __restrict__ probs,
                                             const ushort* __restrict__ vbb,
                                             ushort* __restrict__ pvb){
  __shared__ ushort Pa[64][72];
  __shared__ ushort Vt[64][72];
  const int t = threadIdx.x;
  const int bh = blockIdx.y; const int b = bh / NH, h = bh % NH;
  const int i0 = blockIdx.x * 64;
  const int w = t >> 6, lane = t & 63;
  const int lr = lane & 15, ks = lane >> 4;
  const float* Ap = probs + (size_t)bh * LL * LL;

  f32x4 acc[4];
  #pragma unroll
  for (int n = 0; n < 4; n++)
    #pragma unroll
    for (int r = 0; r < 4; r++) acc[n][r] = 0.f;

  for (int jt = 0; jt < 5; jt++){
    int j0 = jt * 64;
    #pragma unroll
    for (int q = 0; q < 4; q++){
      int idx = t + q*256;
      int i = idx >> 4, jv = idx & 15;
      float4 v = *reinterpret_cast<const float4*>(Ap + (size_t)(i0 + i) * LL + j0 + jv*4);
      ushort4 u; u.x = f2b(v.x); u.y = f2b(v.y); u.z = f2b(v.z); u.w = f2b(v.w);
      *reinterpret_cast<ushort4*>(&Pa[i][jv*4]) = u;
    }
    #pragma unroll
    for (int q = 0; q < 4; q++){
      int idx = t + q*256;
      int j = idx >> 4, dv = idx & 15;
      ushort4 u = *reinterpret_cast<const ushort4*>(
          vbb + (size_t)(b * LL + j0 + j) * 768 + h*64 + dv*4);
      Vt[dv*4+0][j] = u.x; Vt[dv*4+1][j] = u.y;
      Vt[dv*4+2][j] = u.z; Vt[dv*4+3][j] = u.w;
    }
    __syncthreads();
    #pragma unroll
    for (int n = 0; n < 4; n++)
      #pragma unroll
      for (int kt = 0; kt < 2; kt++){
        s16x8 a = *reinterpret_cast<const s16x8*>(&Pa[w*16 + lr][kt*32 + ks*8]);
        s16x8 bb = *reinterpret_cast<const s16x8*>(&Vt[n*16 + lr][kt*32 + ks*8]);
        acc[n] = __builtin_amdgcn_mfma_f32_16x16x32_bf16(a, bb, acc[n], 0, 0, 0);
      }
    __syncthreads();
  }
  #pragma unroll
  for (int n = 0; n < 4; n++)
    #pragma unroll
    for (int r = 0; r < 4; r++){
      int i = w*16 + ks*4 + r;
      int d = n*16 + lr;
      pvb[(size_t)(b * LL + i0 + i) * 768 + h*64 + d] = f2b(acc[n][r]);
    }
}

// ---------------- CE ----------------
__global__ __launch_bounds__(256) void init_ord_k(int* __restrict__ ordbuf, int n){
  int i = blockIdx.x * 256 + threadIdx.x;
  if (i < n) ordbuf[i] = i & 255;
}

__global__ __launch_bounds__(256) void ce_rank_k(const float* __restrict__ at,
                                                 int* __restrict__ ordbuf){
  __shared__ float a[256];
  int b = blockIdx.x, t = threadIdx.x;
  a[t] = at[b * LSN + t];
  __syncthreads();
  float mine = a[t];
  int rank = 0;
  for (int k = 0; k < 256; k++){
    float ak = a[k];
    rank += (ak > mine) || (ak == mine && k < t);
  }
  if (rank >= 0 && rank < 256) ordbuf[b * LSN + rank] = t;
}

__global__ __launch_bounds__(256) void ce_emit_k(const int* __restrict__ ordbuf,
                                                 const int* __restrict__ gidx,
                                                 const int* __restrict__ gt,
                                                 float* __restrict__ out_keep,
                                                 float* __restrict__ out_rem,
                                                 float* __restrict__ out_git){
  int b = blockIdx.x, t = threadIdx.x;
  int o = ordbuf[b * LSN + t];
  o = min(max(o, 0), 255);
  int idx = gidx[b * LSN + o];
  if (t < NKEEP) out_keep[b * NKEEP + t] = (float)idx;
  else           out_rem[b * NREM + (t - NKEEP)] = (float)idx;
  if (t < LT)    out_git[b * LT + t] = (float)gt[b * LT + t];
}

// ---------------- gather ----------------
__global__ __launch_bounds__(256) void gather_k(const float* __restrict__ xnew,
                                                const int* __restrict__ ordbuf,
                                                float* __restrict__ x2){
  int row = blockIdx.x;
  int b = row / LP, r = row % LP;
  int o = (r < LT) ? 0 : ordbuf[b * LSN + (r - LT)];
  o = min(max(o, 0), 255);
  int src = (r < LT) ? r : (LT + o);
  const float* s = xnew + ((size_t)b * LL + src) * CC;
  float* d = x2 + (size_t)row * CC;
  for (int i = threadIdx.x; i < CC; i += 256) d[i] = s[i];
}

// ---------------- elementwise ----------------
__global__ void add_k(float* __restrict__ d, const float* __restrict__ s, size_t n){
  size_t i = (size_t)blockIdx.x * 256 + threadIdx.x;
  size_t st = (size_t)gridDim.x * 256;
  for (; i < n; i += st) d[i] += s[i];
}
__global__ void add2_k(float* __restrict__ d, const float* __restrict__ s0,
                       const float* __restrict__ s1, size_t half){
  size_t i = (size_t)blockIdx.x * 256 + threadIdx.x;
  size_t st = (size_t)gridDim.x * 256;
  for (; i < 2*half; i += st) d[i] += (i < half) ? s0[i] : s1[i - half];
}
__global__ void sentinel_k(float* __restrict__ d, float val, int n){
  int i = blockIdx.x * 256 + threadIdx.x;
  if (i < n) d[i] = val;
}

// ======================================================================
extern "C" void kernel_launch(void* const* d_in, const int* in_sizes, int n_in,
                              void* d_out, int out_size, void* d_ws, size_t ws_size,
                              hipStream_t stream) {
  float* out = (float*)d_out;
  float* ws  = (float*)d_ws;

  static const int EXP[26] = {
    7864320, 7864320, 2048, 2048, 8192, 8192, 1,
    768, 768, 1769472, 589824, 768, 768, 768,
    2359296, 3072, 2359296, 768,
    49152, 64, 49152, 768, 49152, 64, 49152, 768 };

  const void* P[26];
  bool ok = false;
  if (n_in == 26){
    bool m = true; int bad = -1;
    for (int i = 0; i < 26; i++) if (in_sizes[i] != EXP[i]){ m = false; bad = i; break; }
    if (m){ for (int i = 0; i < 26; i++) P[i] = d_in[i]; ok = true; }
    else { sentinel_k<<<16, 256, 0, stream>>>(out, 20000.0f + 16.0f*bad, 4096); return; }
  } else if (n_in == 25){
    bool m = true; int bad = -1;
    for (int i = 0; i < 25; i++){
      int j = (i < 6) ? i : i + 1;
      if (in_sizes[i] != EXP[j]){ m = false; bad = i; break; }
    }
    if (m){
      for (int j = 0; j < 26; j++) P[j] = (j == 6) ? nullptr : d_in[(j < 6) ? j : j - 1];
      ok = true;
    } else { sentinel_k<<<16, 256, 0, stream>>>(out, 20000.0f + 16.0f*bad, 4096); return; }
  }
  if (!ok){ sentinel_k<<<16, 256, 0, stream>>>(out, 10000.0f + 8.0f*n_in, 4096); return; }
  if (out_size != 90656768){
    sentinel_k<<<16, 256, 0, stream>>>(out, 60000.0f + (float)(out_size / 1000000), 4096); return;
  }

  const float* x      = (const float*)P[0];
  const float* xi     = (const float*)P[1];
  const int*   gi_t   = (const int*)P[2];
  const int*   gi_ti  = (const int*)P[3];
  const int*   gi_s   = (const int*)P[4];
  const int*   gi_si  = (const int*)P[5];
  const float* n1_g   = (const float*)P[7];
  const float* n1_b   = (const float*)P[8];
  const float* qkv_w  = (const float*)P[9];
  const float* proj_w = (const float*)P[10];
  const float* proj_b = (const float*)P[11];
  const float* n2_g   = (const float*)P[12];
  const float* n2_b   = (const float*)P[13];
  const float* fc1_w  = (const float*)P[14];
  const float* fc1_b  = (const float*)P[15];
  const float* fc2_w  = (const float*)P[16];
  const float* fc2_b  = (const float*)P[17];
  const float* ad1_dw = (const float*)P[18];
  const float* ad1_db = (const float*)P[19];
  const float* ad1_uw = (const float*)P[20];
  const float* ad1_ub = (const float*)P[21];
  const float* ad2_dw = (const float*)P[22];
  const float* ad2_db = (const float*)P[23];
  const float* ad2_uw = (const float*)P[24];
  const float* ad2_ub = (const float*)P[25];

  // output offsets (f32 elements)
  const size_t o_x     = 0;
  const size_t o_git   = 5996544;
  const size_t o_gis   = 5998592;
  const size_t o_rem   = 6004352;
  const size_t o_attn  = 6006784;
  const size_t o_xi    = 45328384;
  const size_t o_giti  = 51324928;
  const size_t o_gisi  = 51326976;
  const size_t o_remi  = 51332736;
  const size_t o_iattn = 51335168;

  // workspace layout (f32 units) — ~381 MB
  const size_t BLC      = (size_t)NB * LL * CC;          // 7,864,320
  const size_t BPC      = (size_t)NB * LP * CC;          // 5,996,544
  const size_t off_ln   = 0;                             // 2*BLC (ln1 f32; B: x2)
  const size_t off_l1b  = off_ln  + 2*BLC;               // BLC (ln1 bf16)
  const size_t off_k    = off_l1b + BLC;                 // 2*BLC (K f32; late-A: pvb; B: hidb..)
  const size_t off_qb   = off_k   + 2*BLC;               // BLC (Q bf16; B: hidb)
  const size_t off_kb   = off_qb  + BLC;                 // BLC (K bf16; B: hidb)
  const size_t off_vb   = off_kb  + BLC;                 // BLC (V bf16)
  const size_t off_lnt  = off_vb  + BLC;                 // 3,145,728 (template ln f32)
  const size_t off_qt   = off_lnt + 3145728;             // 3,145,728 (Qt f32)
  const size_t off_xnew = off_qt  + 3145728;             // 2*BLC (xnew; B: ln2 f32)
  const size_t off_l2b  = off_xnew+ 2*BLC;               // BPC (ln2 bf16)
  const size_t off_mixh = off_l2b + BPC;                 // 655,360
  const size_t off_att  = off_mixh+ 655360;              // 16,384
  const size_t off_attp = off_att + 16384;               // 196,608 (f64 partials)
  const size_t off_ord  = off_attp+ 196608;              // 16,384
  const size_t off_wts  = off_ord + 16384;               // 3,342,336
  const size_t total_f  = off_wts + 3342336;             // 95,354,880 f32 = 381 MB
  if (ws_size < total_f * sizeof(float)){
    sentinel_k<<<16, 256, 0, stream>>>(out, 40000.0f + (float)(ws_size >> 20), 4096);
    return;
  }

  int* ordbuf = (int*)(ws + off_ord);
  double* attp = (double*)(ws + off_attp);
  ushort* wts = (ushort*)(ws + off_wts);
  ushort* Wt_q    = wts;                 // [768][768]
  ushort* Wt_v    = wts + 589824;        // [768][768]
  ushort* Wt_proj = wts + 1179648;       // [768][768]
  ushort* Wt_fc1  = wts + 1769472;       // [3072][768]
  ushort* Wt_fc2  = wts + 4128768;       // [768][3072]
  ushort* Wt_a1d  = wts + 6488064;       // [64][768]
  ushort* Wt_a1u  = wts + 6537216;       // [768][64]
  ushort* Wt_a2d  = wts + 6586368;       // [64][768]
  ushort* Wt_a2u  = wts + 6635520;       // [768][64]
  ushort* ln1b = (ushort*)(ws + off_l1b);
  ushort* qb   = (ushort*)(ws + off_qb);
  ushort* kb   = (ushort*)(ws + off_kb);
  ushort* vbb  = (ushort*)(ws + off_vb);
  ushort* pvb  = (ushort*)(ws + off_k);    // aliases dead K f32 region (late phase A)
  ushort* ln2b = (ushort*)(ws + off_l2b);
  ushort* mixhb= (ushort*)(ws + off_mixh);

  // ---- weight convert+transpose (bf16) ----
  tconv_k<<<dim3(24, 24), 256, 0, stream>>>(qkv_w,  Wt_q,    768, 768,  2304, 0);
  tconv_k<<<dim3(24, 24), 256, 0, stream>>>(qkv_w,  Wt_v,    768, 768,  2304, 1536);
  tconv_k<<<dim3(24, 24), 256, 0, stream>>>(proj_w, Wt_proj, 768, 768,  768,  0);
  tconv_k<<<dim3(96, 24), 256, 0, stream>>>(fc1_w,  Wt_fc1,  768, 3072, 3072, 0);
  tconv_k<<<dim3(24, 96), 256, 0, stream>>>(fc2_w,  Wt_fc2,  3072, 768, 768,  0);
  tconv_k<<<dim3(2,  24), 256, 0, stream>>>(ad1_dw, Wt_a1d,  768, 64,   64,   0);
  tconv_k<<<dim3(24, 2 ), 256, 0, stream>>>(ad1_uw, Wt_a1u,  64,  768,  768,  0);
  tconv_k<<<dim3(2,  24), 256, 0, stream>>>(ad2_dw, Wt_a2d,  768, 64,   64,   0);
  tconv_k<<<dim3(24, 2 ), 256, 0, stream>>>(ad2_uw, Wt_a2u,  64,  768,  768,  0);

  // ---- Phase A: LN1, template gather, adapter-down, K/Qt/Q/V projections ----
  ln_k<<<NB*LL, 256, 0, stream>>>(x,  n1_g, n1_b, ws + off_ln,       ln1b);
  ln_k<<<NB*LL, 256, 0, stream>>>(xi, n1_g, n1_b, ws + off_ln + BLC, ln1b + BLC);
  copyt_k<<<2*NB*64, 256, 0, stream>>>(ws + off_ln, ws + off_lnt);
  mgemm_k<true,false,true,true><<<dim3(1, 160), 256, 0, stream>>>(
      ln1b, Wt_a1d, ad1_db, mixhb, 2*NB*LL, ADH, CC);
  // K f32 (bit-identical) + bf16 mirror, both streams: M = 20480
  gemm2_k<<<dim3(6, 160), 256, 0, stream>>>(
      ws + off_ln, qkv_w + 768, ws + off_k, kb, 2*NB*LL, CC, CC, 2304, CC);
  // Q template f32 (bit-identical): M = 4096
  gemm2_k<<<dim3(6, 32), 256, 0, stream>>>(
      ws + off_lnt, qkv_w, ws + off_qt, nullptr, 2*NB*64, CC, CC, 2304, CC);
  // Q bf16 all rows (spatial consumer) via MFMA
  mgemm_k<false,false,true,true><<<dim3(6, 160), 256, 0, stream>>>(
      ln1b, Wt_q, nullptr, qb, 2*NB*LL, CC, CC);
  // V bf16 both streams via MFMA
  mgemm_k<false,false,true,true><<<dim3(6, 160), 256, 0, stream>>>(
      ln1b, Wt_v, nullptr, vbb, 2*NB*LL, CC, CC);

  // ---- scores: template f32 (bit-identical) + spatial MFMA ----
  for (int s = 0; s < 2; s++){
    float* probs = out + (s ? o_iattn : o_attn);
    scorest_k<<<dim3(5, 1, NB*NH), 256, 0, stream>>>(
        ws + off_qt + (size_t)s * NB * 64 * CC,
        ws + off_k  + (size_t)s * NB * LL * CC, probs);
    sqk_k<<<dim3(4, 5, NB*NH), 256, 0, stream>>>(
        qb + (size_t)s * NB * LL * CC, kb + (size_t)s * NB * LL * CC, probs);
  }
  // ---- softmax + attn_t (K f32 dead after this block) ----
  for (int s = 0; s < 2; s++){
    float* probs = out + (s ? o_iattn : o_attn);
    softmax_k<<<NB*NH*LL/4, 256, 0, stream>>>(probs);
    attnt1_k<<<NB*NH, 256, 0, stream>>>(probs, attp);
    attnt2_k<<<NB, 256, 0, stream>>>(attp, ws + off_att + (size_t)s * NB * LSN);
  }
  // ---- PV (pvb overwrites dead K region) ----
  for (int s = 0; s < 2; s++)
    pvm_k<<<dim3(5, NB*NH), 256, 0, stream>>>(
        out + (s ? o_iattn : o_attn),
        vbb + (size_t)s * NB * LL * CC, pvb + (size_t)s * NB * LL * CC);
  // proj both streams -> xnew, residuals, cross mixers
  mgemm_k<false,false,true,false><<<dim3(6, 160), 256, 0, stream>>>(
      pvb, Wt_proj, proj_b, ws + off_xnew, 2*NB*LL, CC, CC);
  add2_k<<<4096, 256, 0, stream>>>(ws + off_xnew, x, xi, BLC);
  for (int s = 0; s < 2; s++)
    mgemm_k<false,true,true,false><<<dim3(6, 80), 256, 0, stream>>>(
        mixhb + (size_t)(1 - s) * NB * LL * ADH, Wt_a1u, ad1_ub,
        ws + off_xnew + (size_t)s * BLC, NB*LL, CC, ADH);

  // ---- CE ----
  init_ord_k<<<(2*NB*LSN + 255)/256, 256, 0, stream>>>(ordbuf, 2*NB*LSN);
  for (int s = 0; s < 2; s++){
    ce_rank_k<<<NB, 256, 0, stream>>>(
        ws + off_att + (size_t)s * NB * LSN, ordbuf + (size_t)s * NB * LSN);
    ce_emit_k<<<NB, 256, 0, stream>>>(
        ordbuf + (size_t)s * NB * LSN,
        s ? gi_si : gi_s, s ? gi_ti : gi_t,
        out + (s ? o_gisi : o_gis), out + (s ? o_remi : o_rem),
        out + (s ? o_giti : o_git));
    gather_k<<<NB*LP, 256, 0, stream>>>(
        ws + off_xnew + (size_t)s * BLC,
        ordbuf + (size_t)s * NB * LSN,
        ws + off_ln + (size_t)s * BPC);
  }

  // ---- Phase B ----
  float* x2  = ws + off_ln;
  float* ln2 = ws + off_xnew;
  ushort* hidb   = (ushort*)(ws + off_k);   // [15616][3072] bf16 over dead K/qb/kb
  ushort* mixh2b = mixhb;

  ln_k<<<2*NB*LP, 256, 0, stream>>>(x2, n2_g, n2_b, ln2, ln2b);
  mgemm_k<true,false,true,true><<<dim3(1, 122), 256, 0, stream>>>(
      ln2b, Wt_a2d, ad2_db, mixh2b, 2*NB*LP, ADH, CC);
  mgemm_k<true,false,true,true><<<dim3(24, 122), 256, 0, stream>>>(
      ln2b, Wt_fc1, fc1_b, hidb, 2*NB*LP, C4, CC);

  for (int s = 0; s < 2; s++){
    float* xout = out + (s ? o_xi : o_x);
    mgemm_k<false,false,true,false><<<dim3(6, 61), 256, 0, stream>>>(
        mixh2b + (size_t)(1 - s) * NB * LP * ADH, Wt_a2u, ad2_ub, xout, NB*LP, CC, ADH);
    add_k<<<4096, 256, 0, stream>>>(xout, x2 + (size_t)s * BPC, BPC);
    mgemm_k<false,true,true,false><<<dim3(6, 61), 256, 0, stream>>>(
        hidb + (size_t)s * NB * LP * C4, Wt_fc2, fc2_b, xout, NB*LP, CC, C4);
  }
}